// Round 11
// baseline (594.186 us; speedup 1.0000x reference)
//
#include <hip/hip_runtime.h>
#include <hip/hip_bf16.h>
#include <math.h>

#define THREADS 256

// ---------------- problem constants ----------------
constexpr int B_    = 8;
constexpr int C_    = 768;
constexpr int KS_   = 7;
constexpr int F_IN  = 81;
constexpr int F_SO3 = 300;
constexpr int S2_DIM  = 81;
constexpr int SO3_DIM = 969;
constexpr int G_S2  = 48;
constexpr int G_ACT = 4096;
constexpr int G_SO3 = 36864;
constexpr int CKK   = C_ * KS_ * KS_;   // 37632
constexpr int CKK4  = CKK / 4;          // 9408
constexpr int NPAIR = F_IN * S2_DIM;    // 6561

constexpr int D2_SPLIT = 4;
constexpr int E1_SPLIT = 16;
constexpr int F_SPLIT  = 5;

__constant__ int d_S2_OFF[10]  = {0, 1, 4, 9, 16, 25, 36, 49, 64, 81};
__constant__ int d_SO3_OFF[10] = {0, 1, 10, 35, 84, 165, 286, 455, 680, 969};

struct CEnt { unsigned char u, m, so, l; };
struct CLut { CEnt v[992]; };
constexpr CLut make_clut() {
  CLut t{};
  int S2O[10]  = {0, 1, 4, 9, 16, 25, 36, 49, 64, 81};
  int SO3O[10] = {0, 1, 10, 35, 84, 165, 286, 455, 680, 969};
  for (int i = 0; i < 969; ++i) {
    int l = 0;
    while (i >= SO3O[l + 1]) ++l;
    int d = 2 * l + 1, r = i - SO3O[l];
    t.v[i].u  = (unsigned char)(r / d);
    t.v[i].m  = (unsigned char)(r % d);
    t.v[i].so = (unsigned char)S2O[l];
    t.v[i].l  = (unsigned char)l;
  }
  return t;
}
__constant__ CLut g_clut = make_clut();

// stage-C work items: (l, u, m-quad). 285 items total.
struct CItem { unsigned char l, u, m0; };
struct CItems { CItem v[288]; };
constexpr CItems make_citems() {
  CItems t{};
  int k = 0;
  for (int l = 0; l < 9; ++l) {
    int d = 2 * l + 1;
    for (int u = 0; u < d; ++u)
      for (int m0 = 0; m0 < d; m0 += 4)
        t.v[k++] = {(unsigned char)l, (unsigned char)u, (unsigned char)m0};
  }
  return t;
}
__constant__ CItems g_citems = make_citems();
constexpr int N_CITEMS = 285;

using short8 = __attribute__((ext_vector_type(8))) short;
using f32x4  = __attribute__((ext_vector_type(4))) float;
using f4v    = __attribute__((ext_vector_type(4))) float;

#define GL16(gp, lp)                                                        \
  __builtin_amdgcn_global_load_lds(                                         \
      (const __attribute__((address_space(1))) void*)(gp),                  \
      (__attribute__((address_space(3))) void*)(lp), 16, 0, 0)

#define WAIT_VMCNT6() asm volatile("s_waitcnt vmcnt(6)" ::: "memory")
#define BARRIER()                                   \
  do {                                              \
    __builtin_amdgcn_sched_barrier(0);              \
    __builtin_amdgcn_s_barrier();                   \
    __builtin_amdgcn_sched_barrier(0);              \
  } while (0)

// ---------------- FAST-PATH workspace layout (bytes) ----------------
constexpr size_t AL(size_t x) { return (x + 1023) & ~(size_t)1023; }
constexpr size_t O_Y     = 0;
constexpr size_t O_PSI   = O_Y     + AL((size_t)8 * NPAIR * 4);
constexpr size_t O_ZBF   = O_PSI   + AL((size_t)F_IN * F_SO3 * 81 * 4);
constexpr size_t O_DACT  = O_ZBF   + AL((size_t)2432 * 1024 * 2);
constexpr size_t O_DACTT = O_DACT  + AL((size_t)4096 * 1024 * 2);
constexpr size_t O_WSO3  = O_DACTT + AL((size_t)1024 * 4096 * 2);
constexpr size_t O_DT    = O_WSO3  + AL((size_t)384 * 36864 * 2);
constexpr size_t O_SBF   = O_DT    + AL((size_t)1024 * 36864 * 2);
constexpr size_t O_D2P   = O_SBF   + AL((size_t)2432 * 4096 * 2);
constexpr size_t O_E1P   = O_D2P   + AL((size_t)D2_SPLIT * 2432 * 1024 * 4);
constexpr size_t O_PSI2  = O_E1P   + AL((size_t)E1_SPLIT * 384 * 1024 * 4);
constexpr size_t O_SFP   = O_PSI2  + AL((size_t)F_SO3 * SO3_DIM * 4);
constexpr size_t FAST_NEED = O_SFP + AL((size_t)F_SPLIT * 8 * SO3_DIM * 4);

// ---------------- FALLBACK workspace layout (floats) ----------------
constexpr size_t WS_Y    = 0;
constexpr size_t WS_PSI  = 52488;
constexpr size_t WS_Z    = 2020788;
constexpr size_t WS_S    = 4346388;
constexpr size_t WS_Z2   = 14176788;
constexpr size_t WS_P2P  = 16502388;
constexpr size_t WS_PSI2 = 18827988;

// ================= stage A body =================
__device__ __forceinline__ void stage_a_body(
    const float* __restrict__ Fm, const float* __restrict__ x, float* __restrict__ y,
    char* smemc, int blk) {
  const int p0  = blk * 3;
  const int tid = threadIdx.x;
  const f4v* __restrict__ F4 = (const f4v*)Fm;
  const f4v* __restrict__ x4 = (const f4v*)x;

  float acc[3][8];
#pragma unroll
  for (int p = 0; p < 3; ++p)
#pragma unroll
    for (int b = 0; b < 8; ++b) acc[p][b] = 0.f;

  for (int i = tid; i < CKK4; i += THREADS) {
    f4v xv[8];
#pragma unroll
    for (int b = 0; b < 8; ++b) xv[b] = x4[b * CKK4 + i];
#pragma unroll
    for (int p = 0; p < 3; ++p) {
      f4v fv = __builtin_nontemporal_load(&F4[(size_t)(p0 + p) * CKK4 + i]);
#pragma unroll
      for (int b = 0; b < 8; ++b)
        acc[p][b] += fv[0] * xv[b][0] + fv[1] * xv[b][1] + fv[2] * xv[b][2] + fv[3] * xv[b][3];
    }
  }

  float (*red)[24] = (float(*)[24])smemc;
  const int lane = tid & 63, wid = tid >> 6;
#pragma unroll
  for (int p = 0; p < 3; ++p) {
#pragma unroll
    for (int b = 0; b < 8; ++b) {
      float v = acc[p][b];
      v += __shfl_down(v, 32);
      v += __shfl_down(v, 16);
      v += __shfl_down(v, 8);
      v += __shfl_down(v, 4);
      v += __shfl_down(v, 2);
      v += __shfl_down(v, 1);
      if (lane == 0) red[wid][p * 8 + b] = v;
    }
  }
  __syncthreads();
  if (tid < 24) {
    float v = red[0][tid] + red[1][tid] + red[2][tid] + red[3][tid];
    int p = tid / 8, b = tid % 8;
    y[(size_t)b * NPAIR + p0 + p] = v;
  }
}

__global__ __launch_bounds__(THREADS) void k_stage_a3(
    const float* __restrict__ Fm, const float* __restrict__ x, float* __restrict__ y) {
  __shared__ __align__(16) char smem[512];
  stage_a_body(Fm, x, y, smem, blockIdx.x);
}

// ================= conversion / psi bodies =================
__device__ __forceinline__ void cvt4_body(const float* __restrict__ src,
                                          __hip_bfloat16* __restrict__ dst,
                                          int R, int Cs, int Cp, int blk) {
  size_t e0 = ((size_t)blk * THREADS + threadIdx.x) * 4;
  int r = (int)(e0 / (unsigned)Cp), c = (int)(e0 % (unsigned)Cp);
  __hip_bfloat16 o[4];
#pragma unroll
  for (int j = 0; j < 4; ++j) {
    float v = (r < R && c + j < Cs) ? src[(size_t)r * Cs + c + j] : 0.f;
    o[j] = __float2bfloat16(v);
  }
  *(ushort4*)(&dst[e0]) = *(const ushort4*)o;
}

__device__ __forceinline__ void tr_body(const float* __restrict__ src,
                                        __hip_bfloat16* __restrict__ dst,
                                        int R, int Cs, size_t dstStride, int bx, int by,
                                        char* smemc) {
  float (*tile)[33] = (float(*)[33])smemc;
  const int c0 = bx * 32, r0 = by * 32;
  const int tx = threadIdx.x & 31, ty = threadIdx.x >> 5;
#pragma unroll
  for (int i = 0; i < 32; i += 8) {
    int r = r0 + ty + i, c = c0 + tx;
    tile[ty + i][tx] = (c < Cs) ? src[(size_t)r * Cs + c] : 0.f;
  }
  __syncthreads();
  const int rp = threadIdx.x & 15;
  const int cl = threadIdx.x >> 4;
#pragma unroll
  for (int j = 0; j < 2; ++j) {
    int cc = cl + 16 * j;
    int c  = c0 + cc;
    if (c < Cs) {
      __hip_bfloat16 o[2];
      o[0] = __float2bfloat16(tile[2 * rp][cc]);
      o[1] = __float2bfloat16(tile[2 * rp + 1][cc]);
      *(ushort2*)(&dst[(size_t)c * dstStride + r0 + 2 * rp]) = *(const ushort2*)o;
    }
  }
}

__device__ __forceinline__ void psi_body(const float* __restrict__ w_s2,
                                         const float* __restrict__ Y,
                                         float* __restrict__ psi_t, int blk) {
  int idx = blk * THREADS + threadIdx.x;
  if (idx >= F_IN * F_SO3 * S2_DIM) return;
  int s  = idx % S2_DIM;
  int t1 = idx / S2_DIM;
  int f  = t1 % F_IN;
  int g  = t1 / F_IN;
  const float* w = w_s2 + ((size_t)f * F_SO3 + g) * G_S2;
  float acc = 0.f;
#pragma unroll 8
  for (int n = 0; n < G_S2; ++n) acc += w[n] * Y[n * S2_DIM + s];
  psi_t[idx] = acc * 0.14433756729740643f;
}

constexpr int UB1 = 4096;
constexpr int UB2 = 3968;
constexpr int UB3 = 13824;
constexpr int UB4 = 35712;
constexpr int UB5 = 7689;
constexpr int UB_TOT = UB1 + UB2 + UB3 + UB4 + UB5;

__global__ __launch_bounds__(THREADS) void k_uber(
    const float* __restrict__ D_act, __hip_bfloat16* __restrict__ Dact_bf,
    __hip_bfloat16* __restrict__ DactT_bf,
    const float* __restrict__ w_so3, __hip_bfloat16* __restrict__ wso3_bf,
    const float* __restrict__ D, __hip_bfloat16* __restrict__ DT_bf,
    const float* __restrict__ w_s2, const float* __restrict__ Y, float* __restrict__ psi_t) {
  __shared__ __align__(16) char smem[4352];
  int b = blockIdx.x;
  if (b < UB1) { cvt4_body(D_act, Dact_bf, G_ACT, SO3_DIM, 1024, b); return; }
  b -= UB1;
  if (b < UB2) { tr_body(D_act, DactT_bf, G_ACT, SO3_DIM, 4096, b % 31, b / 31, smem); return; }
  b -= UB2;
  if (b < UB3) { cvt4_body(w_so3, wso3_bf, F_SO3, G_SO3, G_SO3, b); return; }
  b -= UB3;
  if (b < UB4) { tr_body(D, DT_bf, G_SO3, SO3_DIM, 36864, b % 31, b / 31, smem); return; }
  b -= UB4;
  psi_body(w_s2, Y, psi_t, b);
}

// ================= stage C v2: (l,u,m-quad) items, psl broadcast amortized =================
// LDS stride 84 (pad 81->84, row-16B-aligned, over-read safe: so+m0+3 <= 83).
__global__ __launch_bounds__(THREADS) void k_stage_c_bf(
    const float* __restrict__ y, const float* __restrict__ psi_t,
    __hip_bfloat16* __restrict__ z) {
  const int b = blockIdx.x / F_SO3;
  const int g = blockIdx.x % F_SO3;
  __shared__ float ybl[81 * 84];
  __shared__ float psl[81 * 84];
  const int tid = threadIdx.x;
  const float* pg = psi_t + (size_t)g * NPAIR;
  for (int idx = tid; idx < 81 * 84; idx += THREADS) {
    int f = idx / 84, s = idx - f * 84;
    float yv = 0.f, pv = 0.f;
    if (s < 81) {
      yv = y[(size_t)b * NPAIR + f * 81 + s];
      pv = pg[f * 81 + s];
    }
    ybl[idx] = yv;
    psl[idx] = pv;
  }
  __syncthreads();

  __hip_bfloat16* zrow = z + ((size_t)b * F_SO3 + g) * 1024;
  // zero the pad tail [969,1024)
  if (tid < 1024 - 969) zrow[969 + tid] = __float2bfloat16(0.f);

  for (int it = tid; it < N_CITEMS; it += THREADS) {
    CItem e = g_citems.v[it];
    const int d  = 2 * e.l + 1;
    const int so = d_S2_OFF[e.l];
    const int off = d_SO3_OFF[e.l];
    const int base0 = so + e.m0;
    const int pu = so + e.u;
    float a0 = 0.f, a1 = 0.f, a2 = 0.f, a3 = 0.f;
#pragma unroll 3
    for (int f = 0; f < F_IN; ++f) {
      const float* yb = &ybl[f * 84 + base0];
      float pv = psl[f * 84 + pu];
      a0 += pv * yb[0];
      a1 += pv * yb[1];
      a2 += pv * yb[2];
      a3 += pv * yb[3];
    }
    int nm = d - e.m0;               // 1..4 remaining outputs in this quad
    size_t zo = (size_t)off + (size_t)e.u * d + e.m0;
    zrow[zo] = __float2bfloat16(a0 * (1.0f / 9.0f));
    if (nm > 1) zrow[zo + 1] = __float2bfloat16(a1 * (1.0f / 9.0f));
    if (nm > 2) zrow[zo + 2] = __float2bfloat16(a2 * (1.0f / 9.0f));
    if (nm > 3) zrow[zo + 3] = __float2bfloat16(a3 * (1.0f / 9.0f));
  }
}

// ================= 256-wide 8-wave MFMA GEMM, NT: C = scale*(A @ B^T) =================
// BM=128, BN=256, BK=64; 512 threads (8 waves 2Mx4N, 64x64/wave).
// 3 LDS buffers (144KB); stage ktile g+2 during g; counted vmcnt(6), never 0.
// Epilogue: wave-private LDS staging (stride 68) -> float4/ushort4 coalesced stores.
struct G256 {
  const __hip_bfloat16* A;   // [M][K] rows K-contig
  const __hip_bfloat16* B;   // [N][K] rows K-contig
  void* C;
  int K, kSpan, Ncols;
  float scale;
  size_t splitStride;
  int gx, gy, gz, epi;       // epi 0: fp32 (+split offset); 1: bf16 relu
};

__device__ __forceinline__ void mfma256_body(const G256& g, unsigned lin, char* smem) {
  unsigned nwg = (unsigned)(g.gx * g.gy * g.gz);
  if ((nwg & 7u) == 0u) {
    unsigned q = nwg >> 3;
    lin = (lin & 7u) * q + (lin >> 3);
  }
  const int bxi = (int)(lin % (unsigned)g.gx);
  const unsigned t1 = lin / (unsigned)g.gx;
  const int byi = (int)(t1 % (unsigned)g.gy);
  const int bzi = (int)(t1 / (unsigned)g.gy);

  const int t    = threadIdx.x;      // 0..511
  const int lane = t & 63;
  const int wid  = t >> 6;
  const int wr   = wid >> 2, wc = wid & 3;
  const int bm = byi * 128, bn = bxi * 256;
  const int kBegin = bzi * g.kSpan;
  const int NG = g.kSpan >> 6;

  int aL[2], bL[4];
  const char* aSrc[2];
  const char* bSrc[4];
#pragma unroll
  for (int i = 0; i < 2; ++i) {
    int L = (i * 512 + t) * 16;
    int row = L >> 7;
    int kb  = (L & 127) ^ ((row & 7) << 4);
    aL[i] = L;
    aSrc[i] = (const char*)g.A + ((size_t)(bm + row) * g.K) * 2 + kb;
  }
#pragma unroll
  for (int i = 0; i < 4; ++i) {
    int L = (i * 512 + t) * 16;
    int row = L >> 7;
    int kb  = (L & 127) ^ ((row & 7) << 4);
    bL[i] = L;
    bSrc[i] = (const char*)g.B + ((size_t)(bn + row) * g.K) * 2 + kb;
  }

  auto STAGE = [&](int buf, int kt) {
    size_t ko = (size_t)(kBegin + (kt << 6)) * 2;
    char* Ab = smem + buf * 49152;
    char* Bb = Ab + 16384;
#pragma unroll
    for (int i = 0; i < 2; ++i) GL16(aSrc[i] + ko, Ab + aL[i]);
#pragma unroll
    for (int i = 0; i < 4; ++i) GL16(bSrc[i] + ko, Bb + bL[i]);
  };

  f32x4 acc[4][4] = {};

  STAGE(0, 0);
  STAGE(1, 1);
  WAIT_VMCNT6();
  BARRIER();

  int bi = 0;
  for (int gg = 0; gg < NG; ++gg) {
    char* Ab = smem + bi * 49152;
    char* Bb = Ab + 16384;
    short8 af[2][4], bf[2][4];

#pragma unroll
    for (int kk = 0; kk < 2; ++kk) {
      const int klin = (kk << 6) + ((lane >> 4) << 4);
#pragma unroll
      for (int m = 0; m < 4; ++m) {
        int ra = (wr << 6) + (m << 4) + (lane & 15);
        af[kk][m] = *(const short8*)(Ab + ra * 128 + (klin ^ ((ra & 7) << 4)));
      }
#pragma unroll
      for (int n = 0; n < 4; ++n) {
        int rb = (wc << 6) + (n << 4) + (lane & 15);
        bf[kk][n] = *(const short8*)(Bb + rb * 128 + (klin ^ ((rb & 7) << 4)));
      }
    }
    {
      int b2 = bi + 2; if (b2 >= 3) b2 -= 3;
      int kt2 = (gg + 2 < NG) ? gg + 2 : 0;   // dummy re-stage keeps vmcnt uniform
      STAGE(b2, kt2);
    }
    WAIT_VMCNT6();
    BARRIER();
    __builtin_amdgcn_s_setprio(1);
#pragma unroll
    for (int kk = 0; kk < 2; ++kk)
#pragma unroll
      for (int m = 0; m < 4; ++m)
#pragma unroll
        for (int n = 0; n < 4; ++n)
          acc[m][n] = __builtin_amdgcn_mfma_f32_16x16x32_bf16(af[kk][m], bf[kk][n], acc[m][n], 0, 0, 0);
    __builtin_amdgcn_s_setprio(0);
    BARRIER();

    if (++bi == 3) bi = 0;
  }

  // -------- epilogue: wave-private LDS staging, coalesced stores --------
  float* stg = (float*)(smem + wid * 17408);   // 64 rows x stride 68 floats
#pragma unroll
  for (int m = 0; m < 4; ++m)
#pragma unroll
    for (int n = 0; n < 4; ++n)
#pragma unroll
      for (int r = 0; r < 4; ++r)
        stg[(m * 16 + ((lane >> 4) << 2) + r) * 68 + n * 16 + (lane & 15)] = acc[m][n][r];

  const int rowbase = bm + (wr << 6);
  const int colbase = bn + (wc << 6);
  if (g.epi == 0) {
    float* C = (float*)g.C + (size_t)bzi * g.splitStride;
#pragma unroll
    for (int itv = 0; itv < 16; ++itv) {
      int row  = itv * 4 + (lane >> 4);
      int col4 = (lane & 15) * 4;
      f4v v = *(const f4v*)&stg[row * 68 + col4];
      f4v o = {v[0] * g.scale, v[1] * g.scale, v[2] * g.scale, v[3] * g.scale};
      *(f4v*)&C[(size_t)(rowbase + row) * g.Ncols + colbase + col4] = o;
    }
  } else {
    __hip_bfloat16* C = (__hip_bfloat16*)g.C;
#pragma unroll
    for (int itv = 0; itv < 16; ++itv) {
      int row  = itv * 4 + (lane >> 4);
      int col4 = (lane & 15) * 4;
      f4v v = *(const f4v*)&stg[row * 68 + col4];
      __hip_bfloat16 o[4];
#pragma unroll
      for (int j = 0; j < 4; ++j) o[j] = __float2bfloat16(fmaxf(v[j] * g.scale, 0.f));
      *(ushort4*)&C[(size_t)(rowbase + row) * g.Ncols + colbase + col4] = *(const ushort4*)o;
    }
  }
}

// dispatch 4: E1 (192 blocks) + D1 (304 blocks)
__global__ __launch_bounds__(512) void k_g256_dual(G256 g0, G256 g1, int n0) {
  __shared__ __align__(16) char smem[147456];
  if ((int)blockIdx.x < n0) mfma256_body(g0, blockIdx.x, smem);
  else                      mfma256_body(g1, blockIdx.x - n0, smem);
}

// dispatch 5: D2 (304 blocks) + E1 split-K reduce
__global__ __launch_bounds__(512) void k_g256_d2_e1r(
    G256 g, int n0,
    const float* __restrict__ parts, float* __restrict__ psi2) {
  __shared__ __align__(16) char smem[147456];
  if ((int)blockIdx.x < n0) { mfma256_body(g, blockIdx.x, smem); return; }
  int idx = (int)(blockIdx.x - n0) * 512 + threadIdx.x;
  if (idx >= F_SO3 * SO3_DIM) return;
  int r = idx / SO3_DIM, c = idx % SO3_DIM;
  float a = 0.f;
#pragma unroll
  for (int s = 0; s < E1_SPLIT; ++s) a += parts[(size_t)s * (384 * 1024) + (size_t)r * 1024 + c];
  psi2[(size_t)r * SO3_DIM + c] = a * (1.0f / 192.0f);
}

// ================= stage F partials =================
__global__ __launch_bounds__(THREADS) void k_stage_f_part(
    const float* __restrict__ d2p, const float* __restrict__ psi2, float* __restrict__ partial) {
  const int b  = blockIdx.x / 9;
  const int l  = blockIdx.x % 9;
  const int sp = blockIdx.y;
  const int d = 2 * l + 1, d2 = d * d;
  const int off = d_SO3_OFF[l];
  constexpr size_t SS = (size_t)2432 * 1024;
  __shared__ float zb[10][289];
  __shared__ float pb[10][289];
  const int tid = threadIdx.x;
  float acc[2] = {0.f, 0.f};
  const int fBeg = sp * (F_SO3 / F_SPLIT), fEnd = fBeg + F_SO3 / F_SPLIT;
  for (int fc = fBeg; fc < fEnd; fc += 10) {
    for (int t = tid; t < 10 * d2; t += THREADS) {
      int fl = t / d2, q = t - fl * d2;
      int f  = fc + fl;
      size_t zi = ((size_t)b * F_SO3 + f) * 1024 + off + q;
      float zv = 0.f;
#pragma unroll
      for (int s = 0; s < D2_SPLIT; ++s) zv += d2p[zi + (size_t)s * SS];
      zb[fl][q] = zv * (1.0f / G_ACT);
      pb[fl][q] = psi2[(size_t)f * SO3_DIM + off + q];
    }
    __syncthreads();
#pragma unroll 2
    for (int io = 0; io < 2; ++io) {
      int i = tid + io * THREADS;
      if (i < d2) {
        int v = i / d, m = i - v * d;
        float a = acc[io];
#pragma unroll
        for (int fl = 0; fl < 10; ++fl) {
          float s_ = 0.f;
          for (int u = 0; u < d; ++u)
            s_ += zb[fl][u * d + m] * pb[fl][v * d + u];
          a += s_;
        }
        acc[io] = a;
      }
    }
    __syncthreads();
  }
  for (int io = 0; io < 2; ++io) {
    int i = tid + io * THREADS;
    if (i < d2) partial[((size_t)sp * 8 + b) * SO3_DIM + off + i] = acc[io];
  }
}

__global__ __launch_bounds__(THREADS) void k_stage_f_red(
    const float* __restrict__ partial, float* __restrict__ out) {
  int idx = blockIdx.x * THREADS + threadIdx.x;
  if (idx >= 8 * SO3_DIM) return;
  int b = idx / SO3_DIM, i = idx % SO3_DIM;
  int l = g_clut.v[i].l;
  float a = 0.f;
#pragma unroll
  for (int sp = 0; sp < F_SPLIT; ++sp)
    a += partial[((size_t)sp * 8 + b) * SO3_DIM + i];
  out[(size_t)b * SO3_DIM + i] = a * rsqrtf(300.0f * (float)(2 * l + 1));
}

// ================= fallback fp32 path kernels =================
__global__ __launch_bounds__(THREADS) void k_psi(
    const float* __restrict__ w_s2, const float* __restrict__ Y, float* __restrict__ psi_t) {
  psi_body(w_s2, Y, psi_t, blockIdx.x);
}

__global__ __launch_bounds__(THREADS) void k_stage_c(
    const float* __restrict__ y, const float* __restrict__ psi_t, float* __restrict__ z) {
  const int b = blockIdx.x / F_SO3;
  const int g = blockIdx.x % F_SO3;
  __shared__ float ybl[NPAIR];
  __shared__ float psl[NPAIR];
  const int tid = threadIdx.x;
  const float* pg = psi_t + (size_t)g * NPAIR;
  for (int t = tid; t < NPAIR; t += THREADS) {
    ybl[t] = y[(size_t)b * NPAIR + t];
    psl[t] = pg[t];
  }
  __syncthreads();
  for (int i = tid; i < SO3_DIM; i += THREADS) {
    CEnt e = g_clut.v[i];
    int im = e.so + e.m, iu = e.so + e.u;
    float acc = 0.f;
#pragma unroll 9
    for (int f = 0; f < F_IN; ++f)
      acc += ybl[f * S2_DIM + im] * psl[f * S2_DIM + iu];
    z[((size_t)b * F_SO3 + g) * SO3_DIM + i] = acc * (1.0f / 9.0f);
  }
}

__global__ __launch_bounds__(THREADS) void k_gemm_nt_relu(
    const float* __restrict__ A, const float* __restrict__ Bm, float* __restrict__ Cm,
    int M, int N, int K) {
  __shared__ float As[16][68];
  __shared__ float Bs[16][68];
  const int bm = blockIdx.y * 64, bn = blockIdx.x * 64;
  const int t  = threadIdx.x;
  const int lk = t & 15, lm = t >> 4;
  const int tn = t & 15, tm = t >> 4;
  float acc[4][4] = {};
  for (int k0 = 0; k0 < K; k0 += 16) {
    int gk = k0 + lk;
#pragma unroll
    for (int j = 0; j < 4; ++j) {
      int m  = lm + 16 * j;
      int gm = bm + m;
      As[lk][m] = (gm < M && gk < K) ? A[(size_t)gm * K + gk] : 0.f;
      int gn = bn + m;
      Bs[lk][m] = (gn < N && gk < K) ? Bm[(size_t)gn * K + gk] : 0.f;
    }
    __syncthreads();
#pragma unroll
    for (int k = 0; k < 16; ++k) {
      float4 av = *(const float4*)&As[k][tm * 4];
      float4 bv = *(const float4*)&Bs[k][tn * 4];
      float a[4] = {av.x, av.y, av.z, av.w};
      float bb[4] = {bv.x, bv.y, bv.z, bv.w};
#pragma unroll
      for (int i2 = 0; i2 < 4; ++i2)
#pragma unroll
        for (int j2 = 0; j2 < 4; ++j2)
          acc[i2][j2] += a[i2] * bb[j2];
    }
    __syncthreads();
  }
#pragma unroll
  for (int i2 = 0; i2 < 4; ++i2) {
    int gm = bm + tm * 4 + i2;
    if (gm >= M) continue;
#pragma unroll
    for (int j2 = 0; j2 < 4; ++j2) {
      int gn = bn + tn * 4 + j2;
      if (gn < N) Cm[(size_t)gm * N + gn] = fmaxf(acc[i2][j2], 0.f);
    }
  }
}

__global__ __launch_bounds__(THREADS) void k_gemm_nn(
    const float* __restrict__ A, const float* __restrict__ Bm, float* __restrict__ Cm,
    int M, int N, int K, int kSpan, float scale, size_t cStride) {
  __shared__ float As[16][68];
  __shared__ float Bs[16][68];
  const int bm = blockIdx.y * 64, bn = blockIdx.x * 64;
  const int t   = threadIdx.x;
  const int lk  = t & 15, lm = t >> 4;
  const int ln  = t & 63, lkq = t >> 6;
  const int tn  = t & 15, tm = t >> 4;
  const int kBegin = blockIdx.z * kSpan;
  const int kEnd   = kBegin + kSpan;
  float* C = Cm + (size_t)blockIdx.z * cStride;
  float acc[4][4] = {};
  for (int k0 = kBegin; k0 < kEnd; k0 += 16) {
    {
      int gk = k0 + lk;
#pragma unroll
      for (int j = 0; j < 4; ++j) {
        int m = lm + 16 * j, gm = bm + m;
        As[lk][m] = (gm < M) ? A[(size_t)gm * K + gk] : 0.f;
      }
    }
    {
      int gn = bn + ln;
#pragma unroll
      for (int j = 0; j < 4; ++j) {
        int k = lkq + 4 * j;
        Bs[k][ln] = (gn < N) ? Bm[(size_t)(k0 + k) * N + gn] : 0.f;
      }
    }
    __syncthreads();
#pragma unroll
    for (int k = 0; k < 16; ++k) {
      float4 av = *(const float4*)&As[k][tm * 4];
      float4 bv = *(const float4*)&Bs[k][tn * 4];
      float a[4] = {av.x, av.y, av.z, av.w};
      float bb[4] = {bv.x, bv.y, bv.z, bv.w};
#pragma unroll
      for (int i2 = 0; i2 < 4; ++i2)
#pragma unroll
        for (int j2 = 0; j2 < 4; ++j2)
          acc[i2][j2] += a[i2] * bb[j2];
    }
    __syncthreads();
  }
#pragma unroll
  for (int i2 = 0; i2 < 4; ++i2) {
    int gm = bm + tm * 4 + i2;
    if (gm >= M) continue;
#pragma unroll
    for (int j2 = 0; j2 < 4; ++j2) {
      int gn = bn + tn * 4 + j2;
      if (gn < N) C[(size_t)gm * N + gn] = acc[i2][j2] * scale;
    }
  }
}

__global__ __launch_bounds__(THREADS) void k_reduce_psi2(
    const float* __restrict__ parts, float* __restrict__ psi2) {
  int idx = blockIdx.x * THREADS + threadIdx.x;
  if (idx >= F_SO3 * SO3_DIM) return;
  float acc = 0.f;
#pragma unroll
  for (int s = 0; s < 8; ++s) acc += parts[(size_t)s * (F_SO3 * SO3_DIM) + idx];
  psi2[idx] = acc * (1.0f / 192.0f);
}

__global__ __launch_bounds__(THREADS) void k_stage_f(
    const float* __restrict__ z2, const float* __restrict__ psi2, float* __restrict__ out,
    int zStride) {
  const int b = blockIdx.x / 9;
  const int l = blockIdx.x % 9;
  const int d = 2 * l + 1, d2 = d * d;
  const int off = d_SO3_OFF[l];
  __shared__ float zb[10][289];
  __shared__ float pb[10][289];
  const int tid = threadIdx.x;
  float acc[2] = {0.f, 0.f};
  const float scale = rsqrtf(300.0f * (float)d);
  for (int fc = 0; fc < F_SO3; fc += 10) {
    for (int t = tid; t < 10 * d2; t += THREADS) {
      int fl = t / d2, q = t - fl * d2;
      int f  = fc + fl;
      zb[fl][q] = z2[((size_t)b * F_SO3 + f) * zStride + off + q];
      pb[fl][q] = psi2[(size_t)f * SO3_DIM + off + q];
    }
    __syncthreads();
#pragma unroll 2
    for (int io = 0; io < 2; ++io) {
      int i = tid + io * THREADS;
      if (i < d2) {
        int v = i / d, m = i - v * d;
        float a = acc[io];
#pragma unroll
        for (int fl = 0; fl < 10; ++fl) {
          float s_ = 0.f;
          for (int u = 0; u < d; ++u)
            s_ += zb[fl][u * d + m] * pb[fl][v * d + u];
          a += s_;
        }
        acc[io] = a;
      }
    }
    __syncthreads();
  }
  for (int io = 0; io < 2; ++io) {
    int i = tid + io * THREADS;
    if (i < d2) out[(size_t)b * SO3_DIM + off + i] = acc[io] * scale;
  }
}

// ================= launch =================
extern "C" void kernel_launch(void* const* d_in, const int* in_sizes, int n_in,
                              void* d_out, int out_size, void* d_ws, size_t ws_size,
                              hipStream_t stream) {
  const float* x     = (const float*)d_in[0];
  const float* Fm    = (const float*)d_in[1];
  const float* w_s2  = (const float*)d_in[2];
  const float* Y     = (const float*)d_in[3];
  const float* w_so3 = (const float*)d_in[4];
  const float* D     = (const float*)d_in[5];
  const float* D_act = (const float*)d_in[6];
  float* out = (float*)d_out;

  if (ws_size >= FAST_NEED) {
    char* p = (char*)d_ws;
    float*          y       = (float*)(p + O_Y);
    float*          psi     = (float*)(p + O_PSI);
    __hip_bfloat16* z_bf    = (__hip_bfloat16*)(p + O_ZBF);
    __hip_bfloat16* Dact_bf = (__hip_bfloat16*)(p + O_DACT);
    __hip_bfloat16* DactT_bf= (__hip_bfloat16*)(p + O_DACTT);
    __hip_bfloat16* wso3_bf = (__hip_bfloat16*)(p + O_WSO3);
    __hip_bfloat16* DT_bf   = (__hip_bfloat16*)(p + O_DT);
    __hip_bfloat16* s_bf    = (__hip_bfloat16*)(p + O_SBF);
    float*          d2p     = (float*)(p + O_D2P);
    float*          e1p     = (float*)(p + O_E1P);
    float*          psi2    = (float*)(p + O_PSI2);
    float*          sfp     = (float*)(p + O_SFP);

    // 1) stage A (HBM floor: 987 MB of F)
    k_stage_a3<<<NPAIR / 3, THREADS, 0, stream>>>(Fm, x, y);
    // 2) conversions + psi
    k_uber<<<UB_TOT, THREADS, 0, stream>>>(
        D_act, Dact_bf, DactT_bf, w_so3, wso3_bf, D, DT_bf, w_s2, Y, psi);
    // 3) stage C -> z bf16 (item-based, psl-amortized)
    k_stage_c_bf<<<B_ * F_SO3, THREADS, 0, stream>>>(y, psi, z_bf);

    // 4) dual: E1 (M=384,N=1024,K=36864 split 16) + D1 (M=2432,N=4096,K=1024)
    G256 e1{wso3_bf, DT_bf, e1p, G_SO3, G_SO3 / E1_SPLIT, 1024, 1.f,
            (size_t)384 * 1024, 4, 3, E1_SPLIT, 0};
    G256 d1{z_bf, Dact_bf, s_bf, 1024, 1024, 4096, 1.f, 0, 16, 19, 1, 1};
    int nE1 = 4 * 3 * E1_SPLIT;   // 192
    int nD1 = 16 * 19;            // 304
    k_g256_dual<<<nE1 + nD1, 512, 0, stream>>>(e1, d1, nE1);

    // 5) D2 (M=2432,N=1024,K=4096 split 4) + E1 reduce -> psi2
    G256 d2{s_bf, DactT_bf, d2p, 4096, 4096 / D2_SPLIT, 1024, 1.f,
            (size_t)2432 * 1024, 4, 19, D2_SPLIT, 0};
    int nD2  = 4 * 19 * D2_SPLIT;                       // 304
    int nE1r = (F_SO3 * SO3_DIM + 511) / 512;           // 568
    k_g256_d2_e1r<<<nD2 + nE1r, 512, 0, stream>>>(d2, nD2, e1p, psi2);

    // 6) stage F partials (folds D2 split-reduce + /4096)
    k_stage_f_part<<<dim3(B_ * 9, F_SPLIT), THREADS, 0, stream>>>(d2p, psi2, sfp);
    // 7) final reduce
    k_stage_f_red<<<(8 * SO3_DIM + THREADS - 1) / THREADS, THREADS, 0, stream>>>(sfp, out);
  } else {
    float* ws  = (float*)d_ws;
    float* y    = ws + WS_Y;
    float* psi  = ws + WS_PSI;
    float* z    = ws + WS_Z;
    float* s    = ws + WS_S;
    float* z2   = ws + WS_Z2;
    float* p2p  = ws + WS_P2P;
    float* psi2 = ws + WS_PSI2;

    k_stage_a3<<<NPAIR / 3, THREADS, 0, stream>>>(Fm, x, y);
    k_psi<<<(F_IN * F_SO3 * S2_DIM + THREADS - 1) / THREADS, THREADS, 0, stream>>>(w_s2, Y, psi);
    k_stage_c<<<B_ * F_SO3, THREADS, 0, stream>>>(y, psi, z);
    k_gemm_nt_relu<<<dim3(G_ACT / 64, (B_ * F_SO3 + 63) / 64), THREADS, 0, stream>>>(
        z, D_act, s, B_ * F_SO3, G_ACT, SO3_DIM);
    k_gemm_nn<<<dim3((SO3_DIM + 63) / 64, (B_ * F_SO3 + 63) / 64, 1), THREADS, 0, stream>>>(
        s, D_act, z2, B_ * F_SO3, SO3_DIM, G_ACT, G_ACT, 1.0f / G_ACT, 0);
    k_gemm_nn<<<dim3((SO3_DIM + 63) / 64, (F_SO3 + 63) / 64, 8), THREADS, 0, stream>>>(
        w_so3, D, p2p, F_SO3, SO3_DIM, G_SO3, G_SO3 / 8, 1.0f, (size_t)F_SO3 * SO3_DIM);
    k_reduce_psi2<<<(F_SO3 * SO3_DIM + THREADS - 1) / THREADS, THREADS, 0, stream>>>(p2p, psi2);
    k_stage_f<<<B_ * 9, THREADS, 0, stream>>>(z2, psi2, out, SO3_DIM);
  }
}

// Round 12
// 558.709 us; speedup vs baseline: 1.0635x; 1.0635x over previous
//
#include <hip/hip_runtime.h>
#include <hip/hip_bf16.h>
#include <math.h>

#define THREADS 256

// ---------------- problem constants ----------------
constexpr int B_    = 8;
constexpr int C_    = 768;
constexpr int KS_   = 7;
constexpr int F_IN  = 81;
constexpr int F_SO3 = 300;
constexpr int S2_DIM  = 81;
constexpr int SO3_DIM = 969;
constexpr int G_S2  = 48;
constexpr int G_ACT = 4096;
constexpr int G_SO3 = 36864;
constexpr int CKK   = C_ * KS_ * KS_;   // 37632
constexpr int CKK4  = CKK / 4;          // 9408
constexpr int NPAIR = F_IN * S2_DIM;    // 6561

constexpr int D2_SPLIT = 4;
constexpr int E1_SPLIT = 24;
constexpr int F_SPLIT  = 5;

__constant__ int d_S2_OFF[10]  = {0, 1, 4, 9, 16, 25, 36, 49, 64, 81};
__constant__ int d_SO3_OFF[10] = {0, 1, 10, 35, 84, 165, 286, 455, 680, 969};

struct CEnt { unsigned char u, m, so, l; };
struct CLut { CEnt v[992]; };
constexpr CLut make_clut() {
  CLut t{};
  int S2O[10]  = {0, 1, 4, 9, 16, 25, 36, 49, 64, 81};
  int SO3O[10] = {0, 1, 10, 35, 84, 165, 286, 455, 680, 969};
  for (int i = 0; i < 969; ++i) {
    int l = 0;
    while (i >= SO3O[l + 1]) ++l;
    int d = 2 * l + 1, r = i - SO3O[l];
    t.v[i].u  = (unsigned char)(r / d);
    t.v[i].m  = (unsigned char)(r % d);
    t.v[i].so = (unsigned char)S2O[l];
    t.v[i].l  = (unsigned char)l;
  }
  return t;
}
__constant__ CLut g_clut = make_clut();

using short8 = __attribute__((ext_vector_type(8))) short;
using f32x4  = __attribute__((ext_vector_type(4))) float;
using f4v    = __attribute__((ext_vector_type(4))) float;

#define GL16(gp, lp)                                                        \
  __builtin_amdgcn_global_load_lds(                                         \
      (const __attribute__((address_space(1))) void*)(gp),                  \
      (__attribute__((address_space(3))) void*)(lp), 16, 0, 0)

#define WAIT_VMCNT6() asm volatile("s_waitcnt vmcnt(6)" ::: "memory")
#define BARRIER()                                   \
  do {                                              \
    __builtin_amdgcn_sched_barrier(0);              \
    __builtin_amdgcn_s_barrier();                   \
    __builtin_amdgcn_sched_barrier(0);              \
  } while (0)

// ---------------- FAST-PATH workspace layout (bytes) ----------------
constexpr size_t AL(size_t x) { return (x + 1023) & ~(size_t)1023; }
constexpr size_t O_Y     = 0;
constexpr size_t O_PSI   = O_Y     + AL((size_t)8 * NPAIR * 4);
constexpr size_t O_ZBF   = O_PSI   + AL((size_t)F_IN * F_SO3 * 81 * 4);
constexpr size_t O_DACT  = O_ZBF   + AL((size_t)2432 * 1024 * 2);
constexpr size_t O_DACTT = O_DACT  + AL((size_t)4096 * 1024 * 2);
constexpr size_t O_WSO3  = O_DACTT + AL((size_t)1024 * 4096 * 2);
constexpr size_t O_DT    = O_WSO3  + AL((size_t)384 * 36864 * 2);
constexpr size_t O_SBF   = O_DT    + AL((size_t)1024 * 36864 * 2);
constexpr size_t O_D2P   = O_SBF   + AL((size_t)2432 * 4096 * 2);
constexpr size_t O_E1P   = O_D2P   + AL((size_t)D2_SPLIT * 2432 * 1024 * 4);
constexpr size_t O_PSI2  = O_E1P   + AL((size_t)E1_SPLIT * 384 * 1024 * 4);
constexpr size_t O_SFP   = O_PSI2  + AL((size_t)F_SO3 * SO3_DIM * 4);
constexpr size_t FAST_NEED = O_SFP + AL((size_t)F_SPLIT * 8 * SO3_DIM * 4);

// ---------------- FALLBACK workspace layout (floats) ----------------
constexpr size_t WS_Y    = 0;
constexpr size_t WS_PSI  = 52488;
constexpr size_t WS_Z    = 2020788;
constexpr size_t WS_S    = 4346388;
constexpr size_t WS_Z2   = 14176788;
constexpr size_t WS_P2P  = 16502388;
constexpr size_t WS_PSI2 = 18827988;

// ================= stage A body =================
__device__ __forceinline__ void stage_a_body(
    const float* __restrict__ Fm, const float* __restrict__ x, float* __restrict__ y,
    char* smemc, int blk) {
  const int p0  = blk * 3;
  const int tid = threadIdx.x;
  const f4v* __restrict__ F4 = (const f4v*)Fm;
  const f4v* __restrict__ x4 = (const f4v*)x;

  float acc[3][8];
#pragma unroll
  for (int p = 0; p < 3; ++p)
#pragma unroll
    for (int b = 0; b < 8; ++b) acc[p][b] = 0.f;

  for (int i = tid; i < CKK4; i += THREADS) {
    f4v xv[8];
#pragma unroll
    for (int b = 0; b < 8; ++b) xv[b] = x4[b * CKK4 + i];
#pragma unroll
    for (int p = 0; p < 3; ++p) {
      f4v fv = __builtin_nontemporal_load(&F4[(size_t)(p0 + p) * CKK4 + i]);
#pragma unroll
      for (int b = 0; b < 8; ++b)
        acc[p][b] += fv[0] * xv[b][0] + fv[1] * xv[b][1] + fv[2] * xv[b][2] + fv[3] * xv[b][3];
    }
  }

  float (*red)[24] = (float(*)[24])smemc;
  const int lane = tid & 63, wid = tid >> 6;
#pragma unroll
  for (int p = 0; p < 3; ++p) {
#pragma unroll
    for (int b = 0; b < 8; ++b) {
      float v = acc[p][b];
      v += __shfl_down(v, 32);
      v += __shfl_down(v, 16);
      v += __shfl_down(v, 8);
      v += __shfl_down(v, 4);
      v += __shfl_down(v, 2);
      v += __shfl_down(v, 1);
      if (lane == 0) red[wid][p * 8 + b] = v;
    }
  }
  __syncthreads();
  if (tid < 24) {
    float v = red[0][tid] + red[1][tid] + red[2][tid] + red[3][tid];
    int p = tid / 8, b = tid % 8;
    y[(size_t)b * NPAIR + p0 + p] = v;
  }
}

__global__ __launch_bounds__(THREADS) void k_stage_a3(
    const float* __restrict__ Fm, const float* __restrict__ x, float* __restrict__ y) {
  __shared__ __align__(16) char smem[512];
  stage_a_body(Fm, x, y, smem, blockIdx.x);
}

// ================= conversion / psi bodies =================
__device__ __forceinline__ void cvt4_body(const float* __restrict__ src,
                                          __hip_bfloat16* __restrict__ dst,
                                          int R, int Cs, int Cp, int blk) {
  size_t e0 = ((size_t)blk * THREADS + threadIdx.x) * 4;
  int r = (int)(e0 / (unsigned)Cp), c = (int)(e0 % (unsigned)Cp);
  __hip_bfloat16 o[4];
#pragma unroll
  for (int j = 0; j < 4; ++j) {
    float v = (r < R && c + j < Cs) ? src[(size_t)r * Cs + c + j] : 0.f;
    o[j] = __float2bfloat16(v);
  }
  *(ushort4*)(&dst[e0]) = *(const ushort4*)o;
}

__device__ __forceinline__ void tr_body(const float* __restrict__ src,
                                        __hip_bfloat16* __restrict__ dst,
                                        int R, int Cs, size_t dstStride, int bx, int by,
                                        char* smemc) {
  float (*tile)[33] = (float(*)[33])smemc;
  const int c0 = bx * 32, r0 = by * 32;
  const int tx = threadIdx.x & 31, ty = threadIdx.x >> 5;
#pragma unroll
  for (int i = 0; i < 32; i += 8) {
    int r = r0 + ty + i, c = c0 + tx;
    tile[ty + i][tx] = (c < Cs) ? src[(size_t)r * Cs + c] : 0.f;
  }
  __syncthreads();
  const int rp = threadIdx.x & 15;
  const int cl = threadIdx.x >> 4;
#pragma unroll
  for (int j = 0; j < 2; ++j) {
    int cc = cl + 16 * j;
    int c  = c0 + cc;
    if (c < Cs) {
      __hip_bfloat16 o[2];
      o[0] = __float2bfloat16(tile[2 * rp][cc]);
      o[1] = __float2bfloat16(tile[2 * rp + 1][cc]);
      *(ushort2*)(&dst[(size_t)c * dstStride + r0 + 2 * rp]) = *(const ushort2*)o;
    }
  }
}

__device__ __forceinline__ void psi_body(const float* __restrict__ w_s2,
                                         const float* __restrict__ Y,
                                         float* __restrict__ psi_t, int blk) {
  int idx = blk * THREADS + threadIdx.x;
  if (idx >= F_IN * F_SO3 * S2_DIM) return;
  int s  = idx % S2_DIM;
  int t1 = idx / S2_DIM;
  int f  = t1 % F_IN;
  int g  = t1 / F_IN;
  const float* w = w_s2 + ((size_t)f * F_SO3 + g) * G_S2;
  float acc = 0.f;
#pragma unroll 8
  for (int n = 0; n < G_S2; ++n) acc += w[n] * Y[n * S2_DIM + s];
  psi_t[idx] = acc * 0.14433756729740643f;
}

constexpr int UB1 = 4096;
constexpr int UB2 = 3968;
constexpr int UB3 = 13824;
constexpr int UB4 = 35712;
constexpr int UB5 = 7689;
constexpr int UB_TOT = UB1 + UB2 + UB3 + UB4 + UB5;

__global__ __launch_bounds__(THREADS) void k_uber(
    const float* __restrict__ D_act, __hip_bfloat16* __restrict__ Dact_bf,
    __hip_bfloat16* __restrict__ DactT_bf,
    const float* __restrict__ w_so3, __hip_bfloat16* __restrict__ wso3_bf,
    const float* __restrict__ D, __hip_bfloat16* __restrict__ DT_bf,
    const float* __restrict__ w_s2, const float* __restrict__ Y, float* __restrict__ psi_t) {
  __shared__ __align__(16) char smem[4352];
  int b = blockIdx.x;
  if (b < UB1) { cvt4_body(D_act, Dact_bf, G_ACT, SO3_DIM, 1024, b); return; }
  b -= UB1;
  if (b < UB2) { tr_body(D_act, DactT_bf, G_ACT, SO3_DIM, 4096, b % 31, b / 31, smem); return; }
  b -= UB2;
  if (b < UB3) { cvt4_body(w_so3, wso3_bf, F_SO3, G_SO3, G_SO3, b); return; }
  b -= UB3;
  if (b < UB4) { tr_body(D, DT_bf, G_SO3, SO3_DIM, 36864, b % 31, b / 31, smem); return; }
  b -= UB4;
  psi_body(w_s2, Y, psi_t, b);
}

// ================= stage C (bf16 out, stride 1024; psi_t layout) =================
__global__ __launch_bounds__(THREADS) void k_stage_c_bf(
    const float* __restrict__ y, const float* __restrict__ psi_t,
    __hip_bfloat16* __restrict__ z) {
  const int b = blockIdx.x / F_SO3;
  const int g = blockIdx.x % F_SO3;
  __shared__ float ybl[NPAIR];
  __shared__ float psl[NPAIR];
  const int tid = threadIdx.x;
  const float* pg = psi_t + (size_t)g * NPAIR;
  for (int t = tid; t < NPAIR; t += THREADS) {
    ybl[t] = y[(size_t)b * NPAIR + t];
    psl[t] = pg[t];
  }
  __syncthreads();
  for (int i = tid; i < 1024; i += THREADS) {
    float acc = 0.f;
    if (i < SO3_DIM) {
      CEnt e = g_clut.v[i];
      int im = e.so + e.m, iu = e.so + e.u;
#pragma unroll 9
      for (int f = 0; f < F_IN; ++f)
        acc += ybl[f * S2_DIM + im] * psl[f * S2_DIM + iu];
      acc *= (1.0f / 9.0f);
    }
    z[((size_t)b * F_SO3 + g) * 1024 + i] = __float2bfloat16(acc);
  }
}

// ================= 256-wide 8-wave MFMA GEMM, NT: C = scale*(A @ B^T) =================
// BM=128, BN=256, BK=64; 512 threads (8 waves, wave grid 2Mx4N, 64x64/wave).
// LDS: 3 buffers x (A 16KB + B 32KB) = 144KB. Pipeline: stage ktile g+2 during g,
// counted vmcnt(6) at group end (never 0). grid=(gx=N/256, gy=M/128, gz=splits).
struct G256 {
  const __hip_bfloat16* A;   // [M][K] rows K-contig
  const __hip_bfloat16* B;   // [N][K] rows K-contig
  void* C;
  int K, kSpan, Ncols;
  float scale;
  size_t splitStride;
  int gx, gy, gz, epi;       // epi 0: fp32 (+split offset); 1: bf16 relu
};

__device__ __forceinline__ void mfma256_body(const G256& g, unsigned lin, char* smem) {
  unsigned nwg = (unsigned)(g.gx * g.gy * g.gz);
  if ((nwg & 7u) == 0u) {
    unsigned q = nwg >> 3;
    lin = (lin & 7u) * q + (lin >> 3);
  }
  const int bxi = (int)(lin % (unsigned)g.gx);
  const unsigned t1 = lin / (unsigned)g.gx;
  const int byi = (int)(t1 % (unsigned)g.gy);
  const int bzi = (int)(t1 / (unsigned)g.gy);

  const int t    = threadIdx.x;      // 0..511
  const int lane = t & 63;
  const int wid  = t >> 6;
  const int wr   = wid >> 2, wc = wid & 3;
  const int bm = byi * 128, bn = bxi * 256;
  const int kBegin = bzi * g.kSpan;
  const int NG = g.kSpan >> 6;

  // staging addresses (linear LDS dest, inverse-swizzled global source)
  int aL[2], bL[4];
  const char* aSrc[2];
  const char* bSrc[4];
#pragma unroll
  for (int i = 0; i < 2; ++i) {
    int L = (i * 512 + t) * 16;
    int row = L >> 7;
    int kb  = (L & 127) ^ ((row & 7) << 4);
    aL[i] = L;
    aSrc[i] = (const char*)g.A + ((size_t)(bm + row) * g.K) * 2 + kb;
  }
#pragma unroll
  for (int i = 0; i < 4; ++i) {
    int L = (i * 512 + t) * 16;
    int row = L >> 7;
    int kb  = (L & 127) ^ ((row & 7) << 4);
    bL[i] = L;
    bSrc[i] = (const char*)g.B + ((size_t)(bn + row) * g.K) * 2 + kb;
  }

  auto STAGE = [&](int buf, int kt) {
    size_t ko = (size_t)(kBegin + (kt << 6)) * 2;
    char* Ab = smem + buf * 49152;
    char* Bb = Ab + 16384;
#pragma unroll
    for (int i = 0; i < 2; ++i) GL16(aSrc[i] + ko, Ab + aL[i]);
#pragma unroll
    for (int i = 0; i < 4; ++i) GL16(bSrc[i] + ko, Bb + bL[i]);
  };

  f32x4 acc[4][4] = {};

  // prologue: ktile0 -> buf0, ktile1 -> buf1
  STAGE(0, 0);
  STAGE(1, 1);
  WAIT_VMCNT6();     // ktile0's 6 loads landed
  BARRIER();

  int bi = 0;
  for (int gg = 0; gg < NG; ++gg) {
    char* Ab = smem + bi * 49152;
    char* Bb = Ab + 16384;
    short8 af[4], bf[4];

    // ---- phase 0 (kk = 0) ----
#pragma unroll
    for (int m = 0; m < 4; ++m) {
      int ra = (wr << 6) + (m << 4) + (lane & 15);
      af[m] = *(const short8*)(Ab + ra * 128 + ((((lane >> 4) << 4)) ^ ((ra & 7) << 4)));
    }
#pragma unroll
    for (int n = 0; n < 4; ++n) {
      int rb = (wc << 6) + (n << 4) + (lane & 15);
      bf[n] = *(const short8*)(Bb + rb * 128 + ((((lane >> 4) << 4)) ^ ((rb & 7) << 4)));
    }
    BARRIER();
    __builtin_amdgcn_s_setprio(1);
#pragma unroll
    for (int m = 0; m < 4; ++m)
#pragma unroll
      for (int n = 0; n < 4; ++n)
        acc[m][n] = __builtin_amdgcn_mfma_f32_16x16x32_bf16(af[m], bf[n], acc[m][n], 0, 0, 0);
    __builtin_amdgcn_s_setprio(0);

    // ---- phase 1 (kk = 1) ----
#pragma unroll
    for (int m = 0; m < 4; ++m) {
      int ra = (wr << 6) + (m << 4) + (lane & 15);
      af[m] = *(const short8*)(Ab + ra * 128 + ((64 + ((lane >> 4) << 4)) ^ ((ra & 7) << 4)));
    }
#pragma unroll
    for (int n = 0; n < 4; ++n) {
      int rb = (wc << 6) + (n << 4) + (lane & 15);
      bf[n] = *(const short8*)(Bb + rb * 128 + ((64 + ((lane >> 4) << 4)) ^ ((rb & 7) << 4)));
    }
    {
      int b2 = bi + 2; if (b2 >= 3) b2 -= 3;
      int kt2 = (gg + 2 < NG) ? gg + 2 : 0;   // dummy re-stage keeps vmcnt counts uniform
      STAGE(b2, kt2);
    }
    WAIT_VMCNT6();   // next ktile's 6 loads landed
    BARRIER();
    __builtin_amdgcn_s_setprio(1);
#pragma unroll
    for (int m = 0; m < 4; ++m)
#pragma unroll
      for (int n = 0; n < 4; ++n)
        acc[m][n] = __builtin_amdgcn_mfma_f32_16x16x32_bf16(af[m], bf[n], acc[m][n], 0, 0, 0);
    __builtin_amdgcn_s_setprio(0);

    if (++bi == 3) bi = 0;
  }

  const int rbase = bm + (wr << 6) + ((lane >> 4) << 2);
  const int cbase = bn + (wc << 6) + (lane & 15);
  if (g.epi == 0) {
    float* C = (float*)g.C + (size_t)bzi * g.splitStride;
#pragma unroll
    for (int m = 0; m < 4; ++m)
#pragma unroll
      for (int n = 0; n < 4; ++n)
#pragma unroll
        for (int r = 0; r < 4; ++r)
          C[(size_t)(rbase + m * 16 + r) * g.Ncols + (cbase + n * 16)] = acc[m][n][r] * g.scale;
  } else {
    __hip_bfloat16* C = (__hip_bfloat16*)g.C;
#pragma unroll
    for (int m = 0; m < 4; ++m)
#pragma unroll
      for (int n = 0; n < 4; ++n)
#pragma unroll
        for (int r = 0; r < 4; ++r)
          C[(size_t)(rbase + m * 16 + r) * g.Ncols + (cbase + n * 16)] =
              __float2bfloat16(fmaxf(acc[m][n][r], 0.f));
  }
}

// dispatch 4: E1 (288 blocks) + D1 (304 blocks), 512 threads
__global__ __launch_bounds__(512) void k_g256_dual(G256 g0, G256 g1, int n0) {
  __shared__ __align__(16) char smem[147456];
  if ((int)blockIdx.x < n0) mfma256_body(g0, blockIdx.x, smem);
  else                      mfma256_body(g1, blockIdx.x - n0, smem);
}

// dispatch 5: D2 (304 blocks) + E1 split-K reduce, 512 threads
__global__ __launch_bounds__(512) void k_g256_d2_e1r(
    G256 g, int n0,
    const float* __restrict__ parts, float* __restrict__ psi2) {
  __shared__ __align__(16) char smem[147456];
  if ((int)blockIdx.x < n0) { mfma256_body(g, blockIdx.x, smem); return; }
  int idx = (int)(blockIdx.x - n0) * 512 + threadIdx.x;
  if (idx >= F_SO3 * SO3_DIM) return;
  int r = idx / SO3_DIM, c = idx % SO3_DIM;
  float a = 0.f;
#pragma unroll 8
  for (int s = 0; s < E1_SPLIT; ++s) a += parts[(size_t)s * (384 * 1024) + (size_t)r * 1024 + c];
  psi2[(size_t)r * SO3_DIM + c] = a * (1.0f / 192.0f);
}

// ================= stage F partials (reads D2 split partials directly) =================
__global__ __launch_bounds__(THREADS) void k_stage_f_part(
    const float* __restrict__ d2p, const float* __restrict__ psi2, float* __restrict__ partial) {
  const int b  = blockIdx.x / 9;
  const int l  = blockIdx.x % 9;
  const int sp = blockIdx.y;
  const int d = 2 * l + 1, d2 = d * d;
  const int off = d_SO3_OFF[l];
  constexpr size_t SS = (size_t)2432 * 1024;
  __shared__ float zb[10][289];
  __shared__ float pb[10][289];
  const int tid = threadIdx.x;
  float acc[2] = {0.f, 0.f};
  const int fBeg = sp * (F_SO3 / F_SPLIT), fEnd = fBeg + F_SO3 / F_SPLIT;
  for (int fc = fBeg; fc < fEnd; fc += 10) {
    for (int t = tid; t < 10 * d2; t += THREADS) {
      int fl = t / d2, q = t - fl * d2;
      int f  = fc + fl;
      size_t zi = ((size_t)b * F_SO3 + f) * 1024 + off + q;
      float zv = 0.f;
#pragma unroll
      for (int s = 0; s < D2_SPLIT; ++s) zv += d2p[zi + (size_t)s * SS];
      zb[fl][q] = zv * (1.0f / G_ACT);
      pb[fl][q] = psi2[(size_t)f * SO3_DIM + off + q];
    }
    __syncthreads();
#pragma unroll 2
    for (int io = 0; io < 2; ++io) {
      int i = tid + io * THREADS;
      if (i < d2) {
        int v = i / d, m = i - v * d;
        float a = acc[io];
#pragma unroll
        for (int fl = 0; fl < 10; ++fl) {
          float s_ = 0.f;
          for (int u = 0; u < d; ++u)
            s_ += zb[fl][u * d + m] * pb[fl][v * d + u];
          a += s_;
        }
        acc[io] = a;
      }
    }
    __syncthreads();
  }
  for (int io = 0; io < 2; ++io) {
    int i = tid + io * THREADS;
    if (i < d2) partial[((size_t)sp * 8 + b) * SO3_DIM + off + i] = acc[io];
  }
}

__global__ __launch_bounds__(THREADS) void k_stage_f_red(
    const float* __restrict__ partial, float* __restrict__ out) {
  int idx = blockIdx.x * THREADS + threadIdx.x;
  if (idx >= 8 * SO3_DIM) return;
  int b = idx / SO3_DIM, i = idx % SO3_DIM;
  int l = g_clut.v[i].l;
  float a = 0.f;
#pragma unroll
  for (int sp = 0; sp < F_SPLIT; ++sp)
    a += partial[((size_t)sp * 8 + b) * SO3_DIM + i];
  out[(size_t)b * SO3_DIM + i] = a * rsqrtf(300.0f * (float)(2 * l + 1));
}

// ================= fallback fp32 path kernels =================
__global__ __launch_bounds__(THREADS) void k_psi(
    const float* __restrict__ w_s2, const float* __restrict__ Y, float* __restrict__ psi_t) {
  psi_body(w_s2, Y, psi_t, blockIdx.x);
}

__global__ __launch_bounds__(THREADS) void k_stage_c(
    const float* __restrict__ y, const float* __restrict__ psi_t, float* __restrict__ z) {
  const int b = blockIdx.x / F_SO3;
  const int g = blockIdx.x % F_SO3;
  __shared__ float ybl[NPAIR];
  __shared__ float psl[NPAIR];
  const int tid = threadIdx.x;
  const float* pg = psi_t + (size_t)g * NPAIR;
  for (int t = tid; t < NPAIR; t += THREADS) {
    ybl[t] = y[(size_t)b * NPAIR + t];
    psl[t] = pg[t];
  }
  __syncthreads();
  for (int i = tid; i < SO3_DIM; i += THREADS) {
    CEnt e = g_clut.v[i];
    int im = e.so + e.m, iu = e.so + e.u;
    float acc = 0.f;
#pragma unroll 9
    for (int f = 0; f < F_IN; ++f)
      acc += ybl[f * S2_DIM + im] * psl[f * S2_DIM + iu];
    z[((size_t)b * F_SO3 + g) * SO3_DIM + i] = acc * (1.0f / 9.0f);
  }
}

__global__ __launch_bounds__(THREADS) void k_gemm_nt_relu(
    const float* __restrict__ A, const float* __restrict__ Bm, float* __restrict__ Cm,
    int M, int N, int K) {
  __shared__ float As[16][68];
  __shared__ float Bs[16][68];
  const int bm = blockIdx.y * 64, bn = blockIdx.x * 64;
  const int t  = threadIdx.x;
  const int lk = t & 15, lm = t >> 4;
  const int tn = t & 15, tm = t >> 4;
  float acc[4][4] = {};
  for (int k0 = 0; k0 < K; k0 += 16) {
    int gk = k0 + lk;
#pragma unroll
    for (int j = 0; j < 4; ++j) {
      int m  = lm + 16 * j;
      int gm = bm + m;
      As[lk][m] = (gm < M && gk < K) ? A[(size_t)gm * K + gk] : 0.f;
      int gn = bn + m;
      Bs[lk][m] = (gn < N && gk < K) ? Bm[(size_t)gn * K + gk] : 0.f;
    }
    __syncthreads();
#pragma unroll
    for (int k = 0; k < 16; ++k) {
      float4 av = *(const float4*)&As[k][tm * 4];
      float4 bv = *(const float4*)&Bs[k][tn * 4];
      float a[4] = {av.x, av.y, av.z, av.w};
      float bb[4] = {bv.x, bv.y, bv.z, bv.w};
#pragma unroll
      for (int i2 = 0; i2 < 4; ++i2)
#pragma unroll
        for (int j2 = 0; j2 < 4; ++j2)
          acc[i2][j2] += a[i2] * bb[j2];
    }
    __syncthreads();
  }
#pragma unroll
  for (int i2 = 0; i2 < 4; ++i2) {
    int gm = bm + tm * 4 + i2;
    if (gm >= M) continue;
#pragma unroll
    for (int j2 = 0; j2 < 4; ++j2) {
      int gn = bn + tn * 4 + j2;
      if (gn < N) Cm[(size_t)gm * N + gn] = fmaxf(acc[i2][j2], 0.f);
    }
  }
}

__global__ __launch_bounds__(THREADS) void k_gemm_nn(
    const float* __restrict__ A, const float* __restrict__ Bm, float* __restrict__ Cm,
    int M, int N, int K, int kSpan, float scale, size_t cStride) {
  __shared__ float As[16][68];
  __shared__ float Bs[16][68];
  const int bm = blockIdx.y * 64, bn = blockIdx.x * 64;
  const int t   = threadIdx.x;
  const int lk  = t & 15, lm = t >> 4;
  const int ln  = t & 63, lkq = t >> 6;
  const int tn  = t & 15, tm = t >> 4;
  const int kBegin = blockIdx.z * kSpan;
  const int kEnd   = kBegin + kSpan;
  float* C = Cm + (size_t)blockIdx.z * cStride;
  float acc[4][4] = {};
  for (int k0 = kBegin; k0 < kEnd; k0 += 16) {
    {
      int gk = k0 + lk;
#pragma unroll
      for (int j = 0; j < 4; ++j) {
        int m = lm + 16 * j, gm = bm + m;
        As[lk][m] = (gm < M) ? A[(size_t)gm * K + gk] : 0.f;
      }
    }
    {
      int gn = bn + ln;
#pragma unroll
      for (int j = 0; j < 4; ++j) {
        int k = lkq + 4 * j;
        Bs[k][ln] = (gn < N) ? Bm[(size_t)(k0 + k) * N + gn] : 0.f;
      }
    }
    __syncthreads();
#pragma unroll
    for (int k = 0; k < 16; ++k) {
      float4 av = *(const float4*)&As[k][tm * 4];
      float4 bv = *(const float4*)&Bs[k][tn * 4];
      float a[4] = {av.x, av.y, av.z, av.w};
      float bb[4] = {bv.x, bv.y, bv.z, bv.w};
#pragma unroll
      for (int i2 = 0; i2 < 4; ++i2)
#pragma unroll
        for (int j2 = 0; j2 < 4; ++j2)
          acc[i2][j2] += a[i2] * bb[j2];
    }
    __syncthreads();
  }
#pragma unroll
  for (int i2 = 0; i2 < 4; ++i2) {
    int gm = bm + tm * 4 + i2;
    if (gm >= M) continue;
#pragma unroll
    for (int j2 = 0; j2 < 4; ++j2) {
      int gn = bn + tn * 4 + j2;
      if (gn < N) C[(size_t)gm * N + gn] = acc[i2][j2] * scale;
    }
  }
}

__global__ __launch_bounds__(THREADS) void k_reduce_psi2(
    const float* __restrict__ parts, float* __restrict__ psi2) {
  int idx = blockIdx.x * THREADS + threadIdx.x;
  if (idx >= F_SO3 * SO3_DIM) return;
  float acc = 0.f;
#pragma unroll
  for (int s = 0; s < 8; ++s) acc += parts[(size_t)s * (F_SO3 * SO3_DIM) + idx];
  psi2[idx] = acc * (1.0f / 192.0f);
}

__global__ __launch_bounds__(THREADS) void k_stage_f(
    const float* __restrict__ z2, const float* __restrict__ psi2, float* __restrict__ out,
    int zStride) {
  const int b = blockIdx.x / 9;
  const int l = blockIdx.x % 9;
  const int d = 2 * l + 1, d2 = d * d;
  const int off = d_SO3_OFF[l];
  __shared__ float zb[10][289];
  __shared__ float pb[10][289];
  const int tid = threadIdx.x;
  float acc[2] = {0.f, 0.f};
  const float scale = rsqrtf(300.0f * (float)d);
  for (int fc = 0; fc < F_SO3; fc += 10) {
    for (int t = tid; t < 10 * d2; t += THREADS) {
      int fl = t / d2, q = t - fl * d2;
      int f  = fc + fl;
      zb[fl][q] = z2[((size_t)b * F_SO3 + f) * zStride + off + q];
      pb[fl][q] = psi2[(size_t)f * SO3_DIM + off + q];
    }
    __syncthreads();
#pragma unroll 2
    for (int io = 0; io < 2; ++io) {
      int i = tid + io * THREADS;
      if (i < d2) {
        int v = i / d, m = i - v * d;
        float a = acc[io];
#pragma unroll
        for (int fl = 0; fl < 10; ++fl) {
          float s_ = 0.f;
          for (int u = 0; u < d; ++u)
            s_ += zb[fl][u * d + m] * pb[fl][v * d + u];
          a += s_;
        }
        acc[io] = a;
      }
    }
    __syncthreads();
  }
  for (int io = 0; io < 2; ++io) {
    int i = tid + io * THREADS;
    if (i < d2) out[(size_t)b * SO3_DIM + off + i] = acc[io] * scale;
  }
}

// ================= launch =================
extern "C" void kernel_launch(void* const* d_in, const int* in_sizes, int n_in,
                              void* d_out, int out_size, void* d_ws, size_t ws_size,
                              hipStream_t stream) {
  const float* x     = (const float*)d_in[0];
  const float* Fm    = (const float*)d_in[1];
  const float* w_s2  = (const float*)d_in[2];
  const float* Y     = (const float*)d_in[3];
  const float* w_so3 = (const float*)d_in[4];
  const float* D     = (const float*)d_in[5];
  const float* D_act = (const float*)d_in[6];
  float* out = (float*)d_out;

  if (ws_size >= FAST_NEED) {
    char* p = (char*)d_ws;
    float*          y       = (float*)(p + O_Y);
    float*          psi     = (float*)(p + O_PSI);
    __hip_bfloat16* z_bf    = (__hip_bfloat16*)(p + O_ZBF);
    __hip_bfloat16* Dact_bf = (__hip_bfloat16*)(p + O_DACT);
    __hip_bfloat16* DactT_bf= (__hip_bfloat16*)(p + O_DACTT);
    __hip_bfloat16* wso3_bf = (__hip_bfloat16*)(p + O_WSO3);
    __hip_bfloat16* DT_bf   = (__hip_bfloat16*)(p + O_DT);
    __hip_bfloat16* s_bf    = (__hip_bfloat16*)(p + O_SBF);
    float*          d2p     = (float*)(p + O_D2P);
    float*          e1p     = (float*)(p + O_E1P);
    float*          psi2    = (float*)(p + O_PSI2);
    float*          sfp     = (float*)(p + O_SFP);

    // 1) stage A (HBM floor: 987 MB of F)
    k_stage_a3<<<NPAIR / 3, THREADS, 0, stream>>>(Fm, x, y);
    // 2) conversions + psi
    k_uber<<<UB_TOT, THREADS, 0, stream>>>(
        D_act, Dact_bf, DactT_bf, w_so3, wso3_bf, D, DT_bf, w_s2, Y, psi);
    // 3) stage C -> z bf16
    k_stage_c_bf<<<B_ * F_SO3, THREADS, 0, stream>>>(y, psi, z_bf);

    // 4) dual 256-wide: E1 (M=384,N=1024,K=36864 split 24) + D1 (M=2432,N=4096,K=1024)
    G256 e1{wso3_bf, DT_bf, e1p, G_SO3, G_SO3 / E1_SPLIT, 1024, 1.f,
            (size_t)384 * 1024, 4, 3, E1_SPLIT, 0};
    G256 d1{z_bf, Dact_bf, s_bf, 1024, 1024, 4096, 1.f, 0, 16, 19, 1, 1};
    int nE1 = 4 * 3 * E1_SPLIT;   // 288
    int nD1 = 16 * 19;            // 304
    k_g256_dual<<<nE1 + nD1, 512, 0, stream>>>(e1, d1, nE1);

    // 5) D2 (M=2432,N=1024,K=4096 split 4) + E1 reduce -> psi2
    G256 d2{s_bf, DactT_bf, d2p, 4096, 4096 / D2_SPLIT, 1024, 1.f,
            (size_t)2432 * 1024, 4, 19, D2_SPLIT, 0};
    int nD2  = 4 * 19 * D2_SPLIT;                       // 304
    int nE1r = (F_SO3 * SO3_DIM + 511) / 512;           // 568
    k_g256_d2_e1r<<<nD2 + nE1r, 512, 0, stream>>>(d2, nD2, e1p, psi2);

    // 6) stage F partials (folds D2 split-reduce + /4096)
    k_stage_f_part<<<dim3(B_ * 9, F_SPLIT), THREADS, 0, stream>>>(d2p, psi2, sfp);
    // 7) final reduce
    k_stage_f_red<<<(8 * SO3_DIM + THREADS - 1) / THREADS, THREADS, 0, stream>>>(sfp, out);
  } else {
    float* ws  = (float*)d_ws;
    float* y    = ws + WS_Y;
    float* psi  = ws + WS_PSI;
    float* z    = ws + WS_Z;
    float* s    = ws + WS_S;
    float* z2   = ws + WS_Z2;
    float* p2p  = ws + WS_P2P;
    float* psi2 = ws + WS_PSI2;

    k_stage_a3<<<NPAIR / 3, THREADS, 0, stream>>>(Fm, x, y);
    k_psi<<<(F_IN * F_SO3 * S2_DIM + THREADS - 1) / THREADS, THREADS, 0, stream>>>(w_s2, Y, psi);
    k_stage_c<<<B_ * F_SO3, THREADS, 0, stream>>>(y, psi, z);
    k_gemm_nt_relu<<<dim3(G_ACT / 64, (B_ * F_SO3 + 63) / 64), THREADS, 0, stream>>>(
        z, D_act, s, B_ * F_SO3, G_ACT, SO3_DIM);
    k_gemm_nn<<<dim3((SO3_DIM + 63) / 64, (B_ * F_SO3 + 63) / 64, 1), THREADS, 0, stream>>>(
        s, D_act, z2, B_ * F_SO3, SO3_DIM, G_ACT, G_ACT, 1.0f / G_ACT, 0);
    k_gemm_nn<<<dim3((SO3_DIM + 63) / 64, (F_SO3 + 63) / 64, 8), THREADS, 0, stream>>>(
        w_so3, D, p2p, F_SO3, SO3_DIM, G_SO3, G_SO3 / 8, 1.0f, (size_t)F_SO3 * SO3_DIM);
    k_reduce_psi2<<<(F_SO3 * SO3_DIM + THREADS - 1) / THREADS, THREADS, 0, stream>>>(p2p, psi2);
    k_stage_f<<<B_ * 9, THREADS, 0, stream>>>(z2, psi2, out, SO3_DIM);
  }
}

// Round 13
// 553.287 us; speedup vs baseline: 1.0739x; 1.0098x over previous
//
#include <hip/hip_runtime.h>
#include <hip/hip_bf16.h>
#include <math.h>

#define THREADS 256

// ---------------- problem constants ----------------
constexpr int B_    = 8;
constexpr int C_    = 768;
constexpr int KS_   = 7;
constexpr int F_IN  = 81;
constexpr int F_SO3 = 300;
constexpr int S2_DIM  = 81;
constexpr int SO3_DIM = 969;
constexpr int G_S2  = 48;
constexpr int G_ACT = 4096;
constexpr int G_SO3 = 36864;
constexpr int CKK   = C_ * KS_ * KS_;   // 37632
constexpr int CKK4  = CKK / 4;          // 9408
constexpr int NPAIR = F_IN * S2_DIM;    // 6561

constexpr int D2_SPLIT = 4;
constexpr int E1_SPLIT = 24;
constexpr int F_SPLIT  = 5;

__constant__ int d_S2_OFF[10]  = {0, 1, 4, 9, 16, 25, 36, 49, 64, 81};
__constant__ int d_SO3_OFF[10] = {0, 1, 10, 35, 84, 165, 286, 455, 680, 969};

struct CEnt { unsigned char u, m, so, l; };
struct CLut { CEnt v[992]; };
constexpr CLut make_clut() {
  CLut t{};
  int S2O[10]  = {0, 1, 4, 9, 16, 25, 36, 49, 64, 81};
  int SO3O[10] = {0, 1, 10, 35, 84, 165, 286, 455, 680, 969};
  for (int i = 0; i < 969; ++i) {
    int l = 0;
    while (i >= SO3O[l + 1]) ++l;
    int d = 2 * l + 1, r = i - SO3O[l];
    t.v[i].u  = (unsigned char)(r / d);
    t.v[i].m  = (unsigned char)(r % d);
    t.v[i].so = (unsigned char)S2O[l];
    t.v[i].l  = (unsigned char)l;
  }
  return t;
}
__constant__ CLut g_clut = make_clut();

using short8 = __attribute__((ext_vector_type(8))) short;
using f32x4  = __attribute__((ext_vector_type(4))) float;
using f4v    = __attribute__((ext_vector_type(4))) float;

#define GL16(gp, lp)                                                        \
  __builtin_amdgcn_global_load_lds(                                         \
      (const __attribute__((address_space(1))) void*)(gp),                  \
      (__attribute__((address_space(3))) void*)(lp), 16, 0, 0)

#define WAIT_VMCNT8() asm volatile("s_waitcnt vmcnt(8)" ::: "memory")
#define LGKM0()                                     \
  do {                                              \
    asm volatile("s_waitcnt lgkmcnt(0)" ::: "memory"); \
    __builtin_amdgcn_sched_barrier(0);              \
  } while (0)
#define BARRIER()                                   \
  do {                                              \
    __builtin_amdgcn_sched_barrier(0);              \
    __builtin_amdgcn_s_barrier();                   \
    __builtin_amdgcn_sched_barrier(0);              \
  } while (0)

// ---------------- FAST-PATH workspace layout (bytes) ----------------
constexpr size_t AL(size_t x) { return (x + 1023) & ~(size_t)1023; }
constexpr size_t O_Y     = 0;
constexpr size_t O_PSI   = O_Y     + AL((size_t)8 * NPAIR * 4);
constexpr size_t O_ZBF   = O_PSI   + AL((size_t)F_IN * F_SO3 * 81 * 4);
constexpr size_t O_DACT  = O_ZBF   + AL((size_t)2432 * 1024 * 2);
constexpr size_t O_DACTT = O_DACT  + AL((size_t)4096 * 1024 * 2);
constexpr size_t O_WSO3  = O_DACTT + AL((size_t)1024 * 4096 * 2);
constexpr size_t O_DT    = O_WSO3  + AL((size_t)384 * 36864 * 2);
constexpr size_t O_SBF   = O_DT    + AL((size_t)1024 * 36864 * 2);
constexpr size_t O_D2P   = O_SBF   + AL((size_t)2432 * 4096 * 2);
constexpr size_t O_E1P   = O_D2P   + AL((size_t)D2_SPLIT * 2432 * 1024 * 4);
constexpr size_t O_PSI2  = O_E1P   + AL((size_t)E1_SPLIT * 384 * 1024 * 4);
constexpr size_t O_SFP   = O_PSI2  + AL((size_t)F_SO3 * SO3_DIM * 4);
constexpr size_t FAST_NEED = O_SFP + AL((size_t)F_SPLIT * 8 * SO3_DIM * 4);

// ---------------- FALLBACK workspace layout (floats) ----------------
constexpr size_t WS_Y    = 0;
constexpr size_t WS_PSI  = 52488;
constexpr size_t WS_Z    = 2020788;
constexpr size_t WS_S    = 4346388;
constexpr size_t WS_Z2   = 14176788;
constexpr size_t WS_P2P  = 16502388;
constexpr size_t WS_PSI2 = 18827988;

// ================= stage A body =================
__device__ __forceinline__ void stage_a_body(
    const float* __restrict__ Fm, const float* __restrict__ x, float* __restrict__ y,
    char* smemc, int blk) {
  const int p0  = blk * 3;
  const int tid = threadIdx.x;
  const f4v* __restrict__ F4 = (const f4v*)Fm;
  const f4v* __restrict__ x4 = (const f4v*)x;

  float acc[3][8];
#pragma unroll
  for (int p = 0; p < 3; ++p)
#pragma unroll
    for (int b = 0; b < 8; ++b) acc[p][b] = 0.f;

  for (int i = tid; i < CKK4; i += THREADS) {
    f4v xv[8];
#pragma unroll
    for (int b = 0; b < 8; ++b) xv[b] = x4[b * CKK4 + i];
#pragma unroll
    for (int p = 0; p < 3; ++p) {
      f4v fv = __builtin_nontemporal_load(&F4[(size_t)(p0 + p) * CKK4 + i]);
#pragma unroll
      for (int b = 0; b < 8; ++b)
        acc[p][b] += fv[0] * xv[b][0] + fv[1] * xv[b][1] + fv[2] * xv[b][2] + fv[3] * xv[b][3];
    }
  }

  float (*red)[24] = (float(*)[24])smemc;
  const int lane = tid & 63, wid = tid >> 6;
#pragma unroll
  for (int p = 0; p < 3; ++p) {
#pragma unroll
    for (int b = 0; b < 8; ++b) {
      float v = acc[p][b];
      v += __shfl_down(v, 32);
      v += __shfl_down(v, 16);
      v += __shfl_down(v, 8);
      v += __shfl_down(v, 4);
      v += __shfl_down(v, 2);
      v += __shfl_down(v, 1);
      if (lane == 0) red[wid][p * 8 + b] = v;
    }
  }
  __syncthreads();
  if (tid < 24) {
    float v = red[0][tid] + red[1][tid] + red[2][tid] + red[3][tid];
    int p = tid / 8, b = tid % 8;
    y[(size_t)b * NPAIR + p0 + p] = v;
  }
}

__global__ __launch_bounds__(THREADS) void k_stage_a3(
    const float* __restrict__ Fm, const float* __restrict__ x, float* __restrict__ y) {
  __shared__ __align__(16) char smem[512];
  stage_a_body(Fm, x, y, smem, blockIdx.x);
}

// ================= conversion / psi bodies =================
__device__ __forceinline__ void cvt4_body(const float* __restrict__ src,
                                          __hip_bfloat16* __restrict__ dst,
                                          int R, int Cs, int Cp, int blk) {
  size_t e0 = ((size_t)blk * THREADS + threadIdx.x) * 4;
  int r = (int)(e0 / (unsigned)Cp), c = (int)(e0 % (unsigned)Cp);
  __hip_bfloat16 o[4];
#pragma unroll
  for (int j = 0; j < 4; ++j) {
    float v = (r < R && c + j < Cs) ? src[(size_t)r * Cs + c + j] : 0.f;
    o[j] = __float2bfloat16(v);
  }
  *(ushort4*)(&dst[e0]) = *(const ushort4*)o;
}

__device__ __forceinline__ void tr_body(const float* __restrict__ src,
                                        __hip_bfloat16* __restrict__ dst,
                                        int R, int Cs, size_t dstStride, int bx, int by,
                                        char* smemc) {
  float (*tile)[33] = (float(*)[33])smemc;
  const int c0 = bx * 32, r0 = by * 32;
  const int tx = threadIdx.x & 31, ty = threadIdx.x >> 5;
#pragma unroll
  for (int i = 0; i < 32; i += 8) {
    int r = r0 + ty + i, c = c0 + tx;
    tile[ty + i][tx] = (c < Cs) ? src[(size_t)r * Cs + c] : 0.f;
  }
  __syncthreads();
  const int rp = threadIdx.x & 15;
  const int cl = threadIdx.x >> 4;
#pragma unroll
  for (int j = 0; j < 2; ++j) {
    int cc = cl + 16 * j;
    int c  = c0 + cc;
    if (c < Cs) {
      __hip_bfloat16 o[2];
      o[0] = __float2bfloat16(tile[2 * rp][cc]);
      o[1] = __float2bfloat16(tile[2 * rp + 1][cc]);
      *(ushort2*)(&dst[(size_t)c * dstStride + r0 + 2 * rp]) = *(const ushort2*)o;
    }
  }
}

__device__ __forceinline__ void psi_body(const float* __restrict__ w_s2,
                                         const float* __restrict__ Y,
                                         float* __restrict__ psi_t, int blk) {
  int idx = blk * THREADS + threadIdx.x;
  if (idx >= F_IN * F_SO3 * S2_DIM) return;
  int s  = idx % S2_DIM;
  int t1 = idx / S2_DIM;
  int f  = t1 % F_IN;
  int g  = t1 / F_IN;
  const float* w = w_s2 + ((size_t)f * F_SO3 + g) * G_S2;
  float acc = 0.f;
#pragma unroll 8
  for (int n = 0; n < G_S2; ++n) acc += w[n] * Y[n * S2_DIM + s];
  psi_t[idx] = acc * 0.14433756729740643f;
}

constexpr int UB1 = 4096;
constexpr int UB2 = 3968;
constexpr int UB3 = 13824;
constexpr int UB4 = 35712;
constexpr int UB5 = 7689;
constexpr int UB_TOT = UB1 + UB2 + UB3 + UB4 + UB5;

__global__ __launch_bounds__(THREADS) void k_uber(
    const float* __restrict__ D_act, __hip_bfloat16* __restrict__ Dact_bf,
    __hip_bfloat16* __restrict__ DactT_bf,
    const float* __restrict__ w_so3, __hip_bfloat16* __restrict__ wso3_bf,
    const float* __restrict__ D, __hip_bfloat16* __restrict__ DT_bf,
    const float* __restrict__ w_s2, const float* __restrict__ Y, float* __restrict__ psi_t) {
  __shared__ __align__(16) char smem[4352];
  int b = blockIdx.x;
  if (b < UB1) { cvt4_body(D_act, Dact_bf, G_ACT, SO3_DIM, 1024, b); return; }
  b -= UB1;
  if (b < UB2) { tr_body(D_act, DactT_bf, G_ACT, SO3_DIM, 4096, b % 31, b / 31, smem); return; }
  b -= UB2;
  if (b < UB3) { cvt4_body(w_so3, wso3_bf, F_SO3, G_SO3, G_SO3, b); return; }
  b -= UB3;
  if (b < UB4) { tr_body(D, DT_bf, G_SO3, SO3_DIM, 36864, b % 31, b / 31, smem); return; }
  b -= UB4;
  psi_body(w_s2, Y, psi_t, b);
}

// ================= stage C (bf16 out, stride 1024; psi_t layout) =================
__global__ __launch_bounds__(THREADS) void k_stage_c_bf(
    const float* __restrict__ y, const float* __restrict__ psi_t,
    __hip_bfloat16* __restrict__ z) {
  const int b = blockIdx.x / F_SO3;
  const int g = blockIdx.x % F_SO3;
  __shared__ float ybl[NPAIR];
  __shared__ float psl[NPAIR];
  const int tid = threadIdx.x;
  const float* pg = psi_t + (size_t)g * NPAIR;
  for (int t = tid; t < NPAIR; t += THREADS) {
    ybl[t] = y[(size_t)b * NPAIR + t];
    psl[t] = pg[t];
  }
  __syncthreads();
  for (int i = tid; i < 1024; i += THREADS) {
    float acc = 0.f;
    if (i < SO3_DIM) {
      CEnt e = g_clut.v[i];
      int im = e.so + e.m, iu = e.so + e.u;
#pragma unroll 9
      for (int f = 0; f < F_IN; ++f)
        acc += ybl[f * S2_DIM + im] * psl[f * S2_DIM + iu];
      acc *= (1.0f / 9.0f);
    }
    z[((size_t)b * F_SO3 + g) * 1024 + i] = __float2bfloat16(acc);
  }
}

// ================= 128x128 4-wave MFMA GEMM, NT: C = scale*(A @ B^T) =================
// BM=BN=128, BK=64; 256 threads (4 waves 2x2, 64x64/wave). 2 LDS buffers (64KB)
// -> 2 independent blocks/CU (stall decorrelation). Depth-1 prefetch, vmcnt(8)
// never 0; explicit lgkmcnt(0)+barrier closes the 2-buffer overwrite hazard.
struct G256 {
  const __hip_bfloat16* A;   // [M][K] rows K-contig
  const __hip_bfloat16* B;   // [N][K] rows K-contig
  void* C;
  int K, kSpan, Ncols;
  float scale;
  size_t splitStride;
  int gx, gy, gz, epi;       // epi 0: fp32 (+split offset); 1: bf16 relu
};

__device__ __forceinline__ void mfma128_body(const G256& g, unsigned lin, char* smem) {
  unsigned nwg = (unsigned)(g.gx * g.gy * g.gz);
  if ((nwg & 7u) == 0u) {
    unsigned q = nwg >> 3;
    lin = (lin & 7u) * q + (lin >> 3);
  }
  const int bxi = (int)(lin % (unsigned)g.gx);
  const unsigned t1 = lin / (unsigned)g.gx;
  const int byi = (int)(t1 % (unsigned)g.gy);
  const int bzi = (int)(t1 / (unsigned)g.gy);

  const int t    = threadIdx.x;      // 0..255
  const int lane = t & 63;
  const int wid  = t >> 6;           // 0..3
  const int wr   = wid >> 1, wc = wid & 1;
  const int bm = byi * 128, bn = bxi * 128;
  const int kBegin = bzi * g.kSpan;
  const int NG = g.kSpan >> 6;

  // staging: A tile 16KB + B tile 16KB, 256 threads x 16B -> 4 rounds each.
  int aL[4], bL[4];
  const char* aSrc[4];
  const char* bSrc[4];
#pragma unroll
  for (int i = 0; i < 4; ++i) {
    int L = (i * 256 + t) * 16;
    int row = L >> 7;
    int kb  = (L & 127) ^ ((row & 7) << 4);
    aL[i] = L;
    aSrc[i] = (const char*)g.A + ((size_t)(bm + row) * g.K) * 2 + kb;
    bL[i] = L;
    bSrc[i] = (const char*)g.B + ((size_t)(bn + row) * g.K) * 2 + kb;
  }

  auto STAGE = [&](int buf, int kt) {
    size_t ko = (size_t)(kBegin + (kt << 6)) * 2;
    char* Ab = smem + buf * 32768;
    char* Bb = Ab + 16384;
#pragma unroll
    for (int i = 0; i < 4; ++i) GL16(aSrc[i] + ko, Ab + aL[i]);
#pragma unroll
    for (int i = 0; i < 4; ++i) GL16(bSrc[i] + ko, Bb + bL[i]);
  };

  f32x4 acc[4][4] = {};

  // prologue: tile0 -> buf0, tile1 -> buf1; wait tile0's 8 loads.
  STAGE(0, 0);
  STAGE(1, 1);
  WAIT_VMCNT8();
  BARRIER();

  int cur = 0;
  for (int gg = 0; gg < NG; ++gg) {
    char* Ab = smem + cur * 32768;
    char* Bb = Ab + 16384;
    short8 af[2][4], bf[2][4];

    // read ALL fragments of tile gg from buf[cur]
#pragma unroll
    for (int kk = 0; kk < 2; ++kk) {
      const int klin = (kk << 6) + ((lane >> 4) << 4);
#pragma unroll
      for (int m = 0; m < 4; ++m) {
        int ra = (wr << 6) + (m << 4) + (lane & 15);
        af[kk][m] = *(const short8*)(Ab + ra * 128 + (klin ^ ((ra & 7) << 4)));
      }
#pragma unroll
      for (int n = 0; n < 4; ++n) {
        int rb = (wc << 6) + (n << 4) + (lane & 15);
        bf[kk][n] = *(const short8*)(Bb + rb * 128 + (klin ^ ((rb & 7) << 4)));
      }
    }
    LGKM0();        // my ds_reads done (values in regs)
    BARRIER();      // ALL waves' reads done -> safe to overwrite buf[cur]
    {
      int kt2 = (gg + 2 < NG) ? gg + 2 : 0;   // dummy at tail keeps vmcnt uniform
      STAGE(cur, kt2);                        // 8 loads into just-read buffer
    }
    WAIT_VMCNT8();  // drains tile gg+1's 8 loads (issued last iteration)
    BARRIER();      // all waves' gg+1 portions landed
    __builtin_amdgcn_s_setprio(1);
#pragma unroll
    for (int kk = 0; kk < 2; ++kk)
#pragma unroll
      for (int m = 0; m < 4; ++m)
#pragma unroll
        for (int n = 0; n < 4; ++n)
          acc[m][n] = __builtin_amdgcn_mfma_f32_16x16x32_bf16(af[kk][m], bf[kk][n], acc[m][n], 0, 0, 0);
    __builtin_amdgcn_s_setprio(0);

    cur ^= 1;
  }

  const int rbase = bm + (wr << 6) + ((lane >> 4) << 2);
  const int cbase = bn + (wc << 6) + (lane & 15);
  if (g.epi == 0) {
    float* C = (float*)g.C + (size_t)bzi * g.splitStride;
#pragma unroll
    for (int m = 0; m < 4; ++m)
#pragma unroll
      for (int n = 0; n < 4; ++n)
#pragma unroll
        for (int r = 0; r < 4; ++r)
          C[(size_t)(rbase + m * 16 + r) * g.Ncols + (cbase + n * 16)] = acc[m][n][r] * g.scale;
  } else {
    __hip_bfloat16* C = (__hip_bfloat16*)g.C;
#pragma unroll
    for (int m = 0; m < 4; ++m)
#pragma unroll
      for (int n = 0; n < 4; ++n)
#pragma unroll
        for (int r = 0; r < 4; ++r)
          C[(size_t)(rbase + m * 16 + r) * g.Ncols + (cbase + n * 16)] =
              __float2bfloat16(fmaxf(acc[m][n][r], 0.f));
  }
}

// dispatch 4: E1 (576 blocks) + D1 (608 blocks), 256 threads
__global__ __launch_bounds__(THREADS) void k_g256_dual(G256 g0, G256 g1, int n0) {
  __shared__ __align__(16) char smem[65536];
  if ((int)blockIdx.x < n0) mfma128_body(g0, blockIdx.x, smem);
  else                      mfma128_body(g1, blockIdx.x - n0, smem);
}

// dispatch 5: D2 (608 blocks) + E1 split-K reduce, 256 threads
__global__ __launch_bounds__(THREADS) void k_g256_d2_e1r(
    G256 g, int n0,
    const float* __restrict__ parts, float* __restrict__ psi2) {
  __shared__ __align__(16) char smem[65536];
  if ((int)blockIdx.x < n0) { mfma128_body(g, blockIdx.x, smem); return; }
  int idx = (int)(blockIdx.x - n0) * THREADS + threadIdx.x;
  if (idx >= F_SO3 * SO3_DIM) return;
  int r = idx / SO3_DIM, c = idx % SO3_DIM;
  float a = 0.f;
#pragma unroll 8
  for (int s = 0; s < E1_SPLIT; ++s) a += parts[(size_t)s * (384 * 1024) + (size_t)r * 1024 + c];
  psi2[(size_t)r * SO3_DIM + c] = a * (1.0f / 192.0f);
}

// ================= stage F partials (reads D2 split partials directly) =================
__global__ __launch_bounds__(THREADS) void k_stage_f_part(
    const float* __restrict__ d2p, const float* __restrict__ psi2, float* __restrict__ partial) {
  const int b  = blockIdx.x / 9;
  const int l  = blockIdx.x % 9;
  const int sp = blockIdx.y;
  const int d = 2 * l + 1, d2 = d * d;
  const int off = d_SO3_OFF[l];
  constexpr size_t SS = (size_t)2432 * 1024;
  __shared__ float zb[10][289];
  __shared__ float pb[10][289];
  const int tid = threadIdx.x;
  float acc[2] = {0.f, 0.f};
  const int fBeg = sp * (F_SO3 / F_SPLIT), fEnd = fBeg + F_SO3 / F_SPLIT;
  for (int fc = fBeg; fc < fEnd; fc += 10) {
    for (int t = tid; t < 10 * d2; t += THREADS) {
      int fl = t / d2, q = t - fl * d2;
      int f  = fc + fl;
      size_t zi = ((size_t)b * F_SO3 + f) * 1024 + off + q;
      float zv = 0.f;
#pragma unroll
      for (int s = 0; s < D2_SPLIT; ++s) zv += d2p[zi + (size_t)s * SS];
      zb[fl][q] = zv * (1.0f / G_ACT);
      pb[fl][q] = psi2[(size_t)f * SO3_DIM + off + q];
    }
    __syncthreads();
#pragma unroll 2
    for (int io = 0; io < 2; ++io) {
      int i = tid + io * THREADS;
      if (i < d2) {
        int v = i / d, m = i - v * d;
        float a = acc[io];
#pragma unroll
        for (int fl = 0; fl < 10; ++fl) {
          float s_ = 0.f;
          for (int u = 0; u < d; ++u)
            s_ += zb[fl][u * d + m] * pb[fl][v * d + u];
          a += s_;
        }
        acc[io] = a;
      }
    }
    __syncthreads();
  }
  for (int io = 0; io < 2; ++io) {
    int i = tid + io * THREADS;
    if (i < d2) partial[((size_t)sp * 8 + b) * SO3_DIM + off + i] = acc[io];
  }
}

__global__ __launch_bounds__(THREADS) void k_stage_f_red(
    const float* __restrict__ partial, float* __restrict__ out) {
  int idx = blockIdx.x * THREADS + threadIdx.x;
  if (idx >= 8 * SO3_DIM) return;
  int b = idx / SO3_DIM, i = idx % SO3_DIM;
  int l = g_clut.v[i].l;
  float a = 0.f;
#pragma unroll
  for (int sp = 0; sp < F_SPLIT; ++sp)
    a += partial[((size_t)sp * 8 + b) * SO3_DIM + i];
  out[(size_t)b * SO3_DIM + i] = a * rsqrtf(300.0f * (float)(2 * l + 1));
}

// ================= fallback fp32 path kernels =================
__global__ __launch_bounds__(THREADS) void k_psi(
    const float* __restrict__ w_s2, const float* __restrict__ Y, float* __restrict__ psi_t) {
  psi_body(w_s2, Y, psi_t, blockIdx.x);
}

__global__ __launch_bounds__(THREADS) void k_stage_c(
    const float* __restrict__ y, const float* __restrict__ psi_t, float* __restrict__ z) {
  const int b = blockIdx.x / F_SO3;
  const int g = blockIdx.x % F_SO3;
  __shared__ float ybl[NPAIR];
  __shared__ float psl[NPAIR];
  const int tid = threadIdx.x;
  const float* pg = psi_t + (size_t)g * NPAIR;
  for (int t = tid; t < NPAIR; t += THREADS) {
    ybl[t] = y[(size_t)b * NPAIR + t];
    psl[t] = pg[t];
  }
  __syncthreads();
  for (int i = tid; i < SO3_DIM; i += THREADS) {
    CEnt e = g_clut.v[i];
    int im = e.so + e.m, iu = e.so + e.u;
    float acc = 0.f;
#pragma unroll 9
    for (int f = 0; f < F_IN; ++f)
      acc += ybl[f * S2_DIM + im] * psl[f * S2_DIM + iu];
    z[((size_t)b * F_SO3 + g) * SO3_DIM + i] = acc * (1.0f / 9.0f);
  }
}

__global__ __launch_bounds__(THREADS) void k_gemm_nt_relu(
    const float* __restrict__ A, const float* __restrict__ Bm, float* __restrict__ Cm,
    int M, int N, int K) {
  __shared__ float As[16][68];
  __shared__ float Bs[16][68];
  const int bm = blockIdx.y * 64, bn = blockIdx.x * 64;
  const int t  = threadIdx.x;
  const int lk = t & 15, lm = t >> 4;
  const int tn = t & 15, tm = t >> 4;
  float acc[4][4] = {};
  for (int k0 = 0; k0 < K; k0 += 16) {
    int gk = k0 + lk;
#pragma unroll
    for (int j = 0; j < 4; ++j) {
      int m  = lm + 16 * j;
      int gm = bm + m;
      As[lk][m] = (gm < M && gk < K) ? A[(size_t)gm * K + gk] : 0.f;
      int gn = bn + m;
      Bs[lk][m] = (gn < N && gk < K) ? Bm[(size_t)gn * K + gk] : 0.f;
    }
    __syncthreads();
#pragma unroll
    for (int k = 0; k < 16; ++k) {
      float4 av = *(const float4*)&As[k][tm * 4];
      float4 bv = *(const float4*)&Bs[k][tn * 4];
      float a[4] = {av.x, av.y, av.z, av.w};
      float bb[4] = {bv.x, bv.y, bv.z, bv.w};
#pragma unroll
      for (int i2 = 0; i2 < 4; ++i2)
#pragma unroll
        for (int j2 = 0; j2 < 4; ++j2)
          acc[i2][j2] += a[i2] * bb[j2];
    }
    __syncthreads();
  }
#pragma unroll
  for (int i2 = 0; i2 < 4; ++i2) {
    int gm = bm + tm * 4 + i2;
    if (gm >= M) continue;
#pragma unroll
    for (int j2 = 0; j2 < 4; ++j2) {
      int gn = bn + tn * 4 + j2;
      if (gn < N) Cm[(size_t)gm * N + gn] = fmaxf(acc[i2][j2], 0.f);
    }
  }
}

__global__ __launch_bounds__(THREADS) void k_gemm_nn(
    const float* __restrict__ A, const float* __restrict__ Bm, float* __restrict__ Cm,
    int M, int N, int K, int kSpan, float scale, size_t cStride) {
  __shared__ float As[16][68];
  __shared__ float Bs[16][68];
  const int bm = blockIdx.y * 64, bn = blockIdx.x * 64;
  const int t   = threadIdx.x;
  const int lk  = t & 15, lm = t >> 4;
  const int ln  = t & 63, lkq = t >> 6;
  const int tn  = t & 15, tm = t >> 4;
  const int kBegin = blockIdx.z * kSpan;
  const int kEnd   = kBegin + kSpan;
  float* C = Cm + (size_t)blockIdx.z * cStride;
  float acc[4][4] = {};
  for (int k0 = kBegin; k0 < kEnd; k0 += 16) {
    {
      int gk = k0 + lk;
#pragma unroll
      for (int j = 0; j < 4; ++j) {
        int m = lm + 16 * j, gm = bm + m;
        As[lk][m] = (gm < M) ? A[(size_t)gm * K + gk] : 0.f;
      }
    }
    {
      int gn = bn + ln;
#pragma unroll
      for (int j = 0; j < 4; ++j) {
        int k = lkq + 4 * j;
        Bs[k][ln] = (gn < N) ? Bm[(size_t)(k0 + k) * N + gn] : 0.f;
      }
    }
    __syncthreads();
#pragma unroll
    for (int k = 0; k < 16; ++k) {
      float4 av = *(const float4*)&As[k][tm * 4];
      float4 bv = *(const float4*)&Bs[k][tn * 4];
      float a[4] = {av.x, av.y, av.z, av.w};
      float bb[4] = {bv.x, bv.y, bv.z, bv.w};
#pragma unroll
      for (int i2 = 0; i2 < 4; ++i2)
#pragma unroll
        for (int j2 = 0; j2 < 4; ++j2)
          acc[i2][j2] += a[i2] * bb[j2];
    }
    __syncthreads();
  }
#pragma unroll
  for (int i2 = 0; i2 < 4; ++i2) {
    int gm = bm + tm * 4 + i2;
    if (gm >= M) continue;
#pragma unroll
    for (int j2 = 0; j2 < 4; ++j2) {
      int gn = bn + tn * 4 + j2;
      if (gn < N) C[(size_t)gm * N + gn] = acc[i2][j2] * scale;
    }
  }
}

__global__ __launch_bounds__(THREADS) void k_reduce_psi2(
    const float* __restrict__ parts, float* __restrict__ psi2) {
  int idx = blockIdx.x * THREADS + threadIdx.x;
  if (idx >= F_SO3 * SO3_DIM) return;
  float acc = 0.f;
#pragma unroll
  for (int s = 0; s < 8; ++s) acc += parts[(size_t)s * (F_SO3 * SO3_DIM) + idx];
  psi2[idx] = acc * (1.0f / 192.0f);
}

__global__ __launch_bounds__(THREADS) void k_stage_f(
    const float* __restrict__ z2, const float* __restrict__ psi2, float* __restrict__ out,
    int zStride) {
  const int b = blockIdx.x / 9;
  const int l = blockIdx.x % 9;
  const int d = 2 * l + 1, d2 = d * d;
  const int off = d_SO3_OFF[l];
  __shared__ float zb[10][289];
  __shared__ float pb[10][289];
  const int tid = threadIdx.x;
  float acc[2] = {0.f, 0.f};
  const float scale = rsqrtf(300.0f * (float)d);
  for (int fc = 0; fc < F_SO3; fc += 10) {
    for (int t = tid; t < 10 * d2; t += THREADS) {
      int fl = t / d2, q = t - fl * d2;
      int f  = fc + fl;
      zb[fl][q] = z2[((size_t)b * F_SO3 + f) * zStride + off + q];
      pb[fl][q] = psi2[(size_t)f * SO3_DIM + off + q];
    }
    __syncthreads();
#pragma unroll 2
    for (int io = 0; io < 2; ++io) {
      int i = tid + io * THREADS;
      if (i < d2) {
        int v = i / d, m = i - v * d;
        float a = acc[io];
#pragma unroll
        for (int fl = 0; fl < 10; ++fl) {
          float s_ = 0.f;
          for (int u = 0; u < d; ++u)
            s_ += zb[fl][u * d + m] * pb[fl][v * d + u];
          a += s_;
        }
        acc[io] = a;
      }
    }
    __syncthreads();
  }
  for (int io = 0; io < 2; ++io) {
    int i = tid + io * THREADS;
    if (i < d2) out[(size_t)b * SO3_DIM + off + i] = acc[io] * scale;
  }
}

// ================= launch =================
extern "C" void kernel_launch(void* const* d_in, const int* in_sizes, int n_in,
                              void* d_out, int out_size, void* d_ws, size_t ws_size,
                              hipStream_t stream) {
  const float* x     = (const float*)d_in[0];
  const float* Fm    = (const float*)d_in[1];
  const float* w_s2  = (const float*)d_in[2];
  const float* Y     = (const float*)d_in[3];
  const float* w_so3 = (const float*)d_in[4];
  const float* D     = (const float*)d_in[5];
  const float* D_act = (const float*)d_in[6];
  float* out = (float*)d_out;

  if (ws_size >= FAST_NEED) {
    char* p = (char*)d_ws;
    float*          y       = (float*)(p + O_Y);
    float*          psi     = (float*)(p + O_PSI);
    __hip_bfloat16* z_bf    = (__hip_bfloat16*)(p + O_ZBF);
    __hip_bfloat16* Dact_bf = (__hip_bfloat16*)(p + O_DACT);
    __hip_bfloat16* DactT_bf= (__hip_bfloat16*)(p + O_DACTT);
    __hip_bfloat16* wso3_bf = (__hip_bfloat16*)(p + O_WSO3);
    __hip_bfloat16* DT_bf   = (__hip_bfloat16*)(p + O_DT);
    __hip_bfloat16* s_bf    = (__hip_bfloat16*)(p + O_SBF);
    float*          d2p     = (float*)(p + O_D2P);
    float*          e1p     = (float*)(p + O_E1P);
    float*          psi2    = (float*)(p + O_PSI2);
    float*          sfp     = (float*)(p + O_SFP);

    // 1) stage A (HBM floor: 987 MB of F)
    k_stage_a3<<<NPAIR / 3, THREADS, 0, stream>>>(Fm, x, y);
    // 2) conversions + psi
    k_uber<<<UB_TOT, THREADS, 0, stream>>>(
        D_act, Dact_bf, DactT_bf, w_so3, wso3_bf, D, DT_bf, w_s2, Y, psi);
    // 3) stage C -> z bf16
    k_stage_c_bf<<<B_ * F_SO3, THREADS, 0, stream>>>(y, psi, z_bf);

    // 4) dual 128x128: E1 (M=384,N=1024,K=36864 split 24) + D1 (M=2432,N=4096,K=1024)
    G256 e1{wso3_bf, DT_bf, e1p, G_SO3, G_SO3 / E1_SPLIT, 1024, 1.f,
            (size_t)384 * 1024, 8, 3, E1_SPLIT, 0};
    G256 d1{z_bf, Dact_bf, s_bf, 1024, 1024, 4096, 1.f, 0, 32, 19, 1, 1};
    int nE1 = 8 * 3 * E1_SPLIT;   // 576
    int nD1 = 32 * 19;            // 608
    k_g256_dual<<<nE1 + nD1, THREADS, 0, stream>>>(e1, d1, nE1);

    // 5) D2 (M=2432,N=1024,K=4096 split 4) + E1 reduce -> psi2
    G256 d2{s_bf, DactT_bf, d2p, 4096, 4096 / D2_SPLIT, 1024, 1.f,
            (size_t)2432 * 1024, 8, 19, D2_SPLIT, 0};
    int nD2  = 8 * 19 * D2_SPLIT;                       // 608
    int nE1r = (F_SO3 * SO3_DIM + THREADS - 1) / THREADS;  // 1136
    k_g256_d2_e1r<<<nD2 + nE1r, THREADS, 0, stream>>>(d2, nD2, e1p, psi2);

    // 6) stage F partials (folds D2 split-reduce + /4096)
    k_stage_f_part<<<dim3(B_ * 9, F_SPLIT), THREADS, 0, stream>>>(d2p, psi2, sfp);
    // 7) final reduce
    k_stage_f_red<<<(8 * SO3_DIM + THREADS - 1) / THREADS, THREADS, 0, stream>>>(sfp, out);
  } else {
    float* ws  = (float*)d_ws;
    float* y    = ws + WS_Y;
    float* psi  = ws + WS_PSI;
    float* z    = ws + WS_Z;
    float* s    = ws + WS_S;
    float* z2   = ws + WS_Z2;
    float* p2p  = ws + WS_P2P;
    float* psi2 = ws + WS_PSI2;

    k_stage_a3<<<NPAIR / 3, THREADS, 0, stream>>>(Fm, x, y);
    k_psi<<<(F_IN * F_SO3 * S2_DIM + THREADS - 1) / THREADS, THREADS, 0, stream>>>(w_s2, Y, psi);
    k_stage_c<<<B_ * F_SO3, THREADS, 0, stream>>>(y, psi, z);
    k_gemm_nt_relu<<<dim3(G_ACT / 64, (B_ * F_SO3 + 63) / 64), THREADS, 0, stream>>>(
        z, D_act, s, B_ * F_SO3, G_ACT, SO3_DIM);
    k_gemm_nn<<<dim3((SO3_DIM + 63) / 64, (B_ * F_SO3 + 63) / 64, 1), THREADS, 0, stream>>>(
        s, D_act, z2, B_ * F_SO3, SO3_DIM, G_ACT, G_ACT, 1.0f / G_ACT, 0);
    k_gemm_nn<<<dim3((SO3_DIM + 63) / 64, (F_SO3 + 63) / 64, 8), THREADS, 0, stream>>>(
        w_so3, D, p2p, F_SO3, SO3_DIM, G_SO3, G_SO3 / 8, 1.0f, (size_t)F_SO3 * SO3_DIM);
    k_reduce_psi2<<<(F_SO3 * SO3_DIM + THREADS - 1) / THREADS, THREADS, 0, stream>>>(p2p, psi2);
    k_stage_f<<<B_ * 9, THREADS, 0, stream>>>(z2, psi2, out, SO3_DIM);
  }
}